// Round 4
// baseline (499.559 us; speedup 1.0000x reference)
//
#include <hip/hip_runtime.h>
#include <hip/hip_bf16.h>

// DIMKT: B=1024, S=200, D=128.
// R10: merge proj into the fused kernel, storm-free. R9 left proj_all as a
// 115us serial region (vs ~15us roofline). R8's merge failed from polling
// storms (all-thread acquire polling), not the merge itself. Here: ALL 256
// blocks run proj chunks first (854/256 ~ 3.3 each), then producers gate items
// on projdone==256 polled by ONE thread/block; scan keeps R9's wm-sweeper
// gating (proven 343us); scan computes Tp1c/Tp2c locally (R8 math, verified).
// zero_sync kernel clears flags each iteration. Fallback: 4-kernel path.

#define S_LEN 200
#define NBATCH 1024
#define DIM 128
#define LOG2E 1.4426950408889634f
#define NPROD 191
#define NBLK 256
#define NCHUNK 854

typedef short short8 __attribute__((ext_vector_type(8)));
typedef float f32x4 __attribute__((ext_vector_type(4)));

__device__ __forceinline__ unsigned short f2b(float f) {
  union { float f; unsigned u; } v; v.f = f;
  unsigned r = (v.u + 0x7FFFu + ((v.u >> 16) & 1u)) >> 16;  // RNE
  return (unsigned short)r;
}
__device__ __forceinline__ float b2f(unsigned short b) {
  union { unsigned u; float f; } v; v.u = ((unsigned)b) << 16;
  return v.f;
}
__device__ __forceinline__ unsigned pk_bf16(float lo, float hi) {
  __hip_bfloat162 t = __float22bfloat162_rn(make_float2(lo, hi));
  union { __hip_bfloat162 h; unsigned u; } cv; cv.h = t;
  return cv.u;
}
__device__ __forceinline__ float fast_sigmoid(float x) {
  return __builtin_amdgcn_rcpf(1.0f + __builtin_amdgcn_exp2f(-LOG2E * x));
}
__device__ __forceinline__ float fast_tanh(float x) {
  return 2.0f * __builtin_amdgcn_rcpf(1.0f + __builtin_amdgcn_exp2f(-2.0f * LOG2E * x)) - 1.0f;
}
// LDS-only barrier: does NOT drain vmcnt, prefetches stay in flight.
__device__ __forceinline__ void wg_barrier_lds() {
  __asm__ volatile("s_waitcnt lgkmcnt(0)\n\ts_barrier" ::: "memory");
}

__global__ void zero_sync_kernel(int* __restrict__ s) { s[threadIdx.x] = 0; }

// ---------------- fallback-only P1: projected embedding tables (256 thr).
__global__ void proj_all_kernel(const float* __restrict__ Eq, const float* __restrict__ Ec,
                                const float* __restrict__ Eqd, const float* __restrict__ Ecd,
                                const float* __restrict__ Ecorr,
                                const float* __restrict__ Wx,
                                const float* __restrict__ Wp1, const float* __restrict__ bp1,
                                const float* __restrict__ Wp2, const float* __restrict__ bp2,
                                const float* __restrict__ Wk, const float* __restrict__ bk,
                                unsigned short* __restrict__ Tq, unsigned short* __restrict__ Tc,
                                unsigned short* __restrict__ Tqd, unsigned short* __restrict__ Tcd,
                                unsigned short* __restrict__ Tkqd, unsigned short* __restrict__ Tkcd,
                                float* __restrict__ Tkc) {
  const int bid = blockIdx.x;
  const int tid = threadIdx.x;
  if (bid >= 802) {
    const int blk = bid - 802;
    if (blk < 101) {
      const int o = tid & 127, half = tid >> 7;
      const float* e = (half ? Ecd : Eqd) + (size_t)blk * DIM;
      const float* wr = Wk + (size_t)o * 512 + (half ? 384 : 256);
      float a = 0.f;
      for (int k = 0; k < DIM; ++k) a = fmaf(e[k], wr[k], a);
      (half ? Tkcd : Tkqd)[blk * DIM + o] = f2b(a);
    } else {
      if (tid < 256) {
        const int e2 = tid >> 7, o = tid & 127;
        const float* ec = Ecorr + e2 * DIM;
        const float* wr = Wk + (size_t)o * 512 + 128;
        float a = bk[o];
        for (int k = 0; k < DIM; ++k) a = fmaf(ec[k], wr[k], a);
        Tkc[e2 * DIM + o] = a;
      }
    }
    return;
  }
  const float* E; int M, coff, r0; unsigned short* T;
  if (bid < 782)      { E = Eq;  M = 50000; coff = 0;   T = Tq;  r0 = bid * 64; }
  else if (bid < 798) { E = Ec;  M = 1000;  coff = 128; T = Tc;  r0 = (bid - 782) * 64; }
  else if (bid < 800) { E = Eqd; M = 101;   coff = 256; T = Tqd; r0 = (bid - 798) * 64; }
  else                { E = Ecd; M = 101;   coff = 384; T = Tcd; r0 = (bid - 800) * 64; }

  __shared__ __align__(16) unsigned short A[64][136];
  {
    const int row = tid >> 2, cb = (tid & 3) * 32;
    union U8 { uint4 v; unsigned short s[8]; } o;
#pragma unroll
    for (int cc = 0; cc < 4; ++cc) {
      const int c8 = cb + cc * 8;
      if (r0 + row < M) {
        const float4 e0 = *(const float4*)(E + (size_t)(r0 + row) * DIM + c8);
        const float4 e1 = *(const float4*)(E + (size_t)(r0 + row) * DIM + c8 + 4);
        o.s[0] = f2b(e0.x); o.s[1] = f2b(e0.y); o.s[2] = f2b(e0.z); o.s[3] = f2b(e0.w);
        o.s[4] = f2b(e1.x); o.s[5] = f2b(e1.y); o.s[6] = f2b(e1.z); o.s[7] = f2b(e1.w);
      } else {
        o.v = make_uint4(0, 0, 0, 0);
      }
      *(uint4*)&A[row][c8] = o.v;
    }
  }
  __syncthreads();
  const int w = tid >> 6, L = tid & 63, q = L >> 4, m = L & 15;
  short8 bf[2][4];
#pragma unroll
  for (int T2 = 0; T2 < 2; ++T2) {
    const int n = 32 * w + 16 * T2 + m;
#pragma unroll
    for (int kb = 0; kb < 4; ++kb) {
      const float* src = Wx + (size_t)n * 512 + coff + kb * 32 + q * 8;
      const float4 v0 = *(const float4*)src;
      const float4 v1 = *(const float4*)(src + 4);
      short8 f;
      f[0] = (short)f2b(v0.x); f[1] = (short)f2b(v0.y);
      f[2] = (short)f2b(v0.z); f[3] = (short)f2b(v0.w);
      f[4] = (short)f2b(v1.x); f[5] = (short)f2b(v1.y);
      f[6] = (short)f2b(v1.z); f[7] = (short)f2b(v1.w);
      bf[T2][kb] = f;
    }
  }
  const f32x4 vzero = {0.f, 0.f, 0.f, 0.f};
#pragma unroll
  for (int mt = 0; mt < 4; ++mt) {
    short8 af[4];
#pragma unroll
    for (int kb = 0; kb < 4; ++kb) af[kb] = *(const short8*)&A[mt * 16 + m][kb * 32 + q * 8];
    f32x4 acc[2] = {vzero, vzero};
#pragma unroll
    for (int kb = 0; kb < 4; ++kb) {
#pragma unroll
      for (int T2 = 0; T2 < 2; ++T2)
        acc[T2] = __builtin_amdgcn_mfma_f32_16x16x32_bf16(af[kb], bf[T2][kb], acc[T2], 0, 0, 0);
    }
#pragma unroll
    for (int T2 = 0; T2 < 2; ++T2) {
      const int col = 32 * w + 16 * T2 + m;
#pragma unroll
      for (int i = 0; i < 4; ++i) {
        const int r = r0 + mt * 16 + q * 4 + i;
        if (r < M) T[(size_t)r * DIM + col] = f2b(acc[T2][i]);
      }
    }
  }
}

// ---------------- fallback-only P2: x build
__global__ void build_x_kernel(const int* __restrict__ qs, const int* __restrict__ cs,
                               const int* __restrict__ qds, const int* __restrict__ cds,
                               const int* __restrict__ corr,
                               const unsigned short* __restrict__ Tq, const unsigned short* __restrict__ Tc,
                               const unsigned short* __restrict__ Tqd, const unsigned short* __restrict__ Tcd,
                               const float* __restrict__ bx, unsigned short* __restrict__ xg,
                               float* __restrict__ SSg, float* __restrict__ corrf) {
  const int r = blockIdx.x * 16 + (threadIdx.x >> 4);   // r = s*1024 + b
  const int c8 = (threadIdx.x & 15) * 8;
  const int s = r >> 10, b = r & 1023;
  const int q = qs[b * S_LEN + s], c = cs[b * S_LEN + s];
  const int qd = qds[b * S_LEN + s], cd = cds[b * S_LEN + s];
  union U8 { uint4 v; unsigned short s[8]; };
  U8 vq, vc, vd, ve, o;
  vq.v = *(const uint4*)(Tq + (size_t)q * DIM + c8);
  vc.v = *(const uint4*)(Tc + (size_t)c * DIM + c8);
  vd.v = *(const uint4*)(Tqd + (size_t)qd * DIM + c8);
  ve.v = *(const uint4*)(Tcd + (size_t)cd * DIM + c8);
  const float4 bx0 = *(const float4*)(bx + c8);
  const float4 bx1 = *(const float4*)(bx + c8 + 4);
  float bb[8] = {bx0.x, bx0.y, bx0.z, bx0.w, bx1.x, bx1.y, bx1.z, bx1.w};
  float part = 0.f;
#pragma unroll
  for (int j = 0; j < 8; ++j) {
    const float sv = b2f(vq.s[j]) + b2f(vc.s[j]) + b2f(vd.s[j]) + b2f(ve.s[j]) + bb[j];
    o.s[j] = f2b(sv);
    const float xr = b2f(o.s[j]);
    part = fmaf(xr, xr, part);
  }
  *(uint4*)(xg + (size_t)r * DIM + c8) = o.v;
#pragma unroll
  for (int off = 1; off <= 8; off <<= 1) part += __shfl_xor(part, off, 64);
  if ((threadIdx.x & 15) == 0) {
    SSg[r] = part;
    corrf[r] = (float)corr[b * S_LEN + s];
  }
}

// ---------------- fallback-only P3: GG gemm
__global__ void gemm_xg_kernel(const unsigned short* __restrict__ xg,
                               const float* __restrict__ Wk,
                               const int* __restrict__ corr, const int* __restrict__ qds,
                               const int* __restrict__ cds,
                               const float* __restrict__ Tkc,
                               const unsigned short* __restrict__ Tkqd,
                               const unsigned short* __restrict__ Tkcd,
                               unsigned short* __restrict__ GG) {
  const int tid = threadIdx.x;
  const int r0 = blockIdx.x * 64;   // r = t*1024 + b, t <= 198
  __shared__ __align__(16) unsigned short TS[64][136];
  {
    const int row = tid >> 2, cb = (tid & 3) * 32;
    const int r = r0 + row, t = r >> 10, b = r & 1023;
    const int ci = corr[b * S_LEN + t], qi = qds[b * S_LEN + t], di = cds[b * S_LEN + t];
    union U8 { uint4 v; unsigned short s[8]; };
#pragma unroll
    for (int cc = 0; cc < 4; ++cc) {
      const int c8 = cb + cc * 8;
      U8 vq, vc, o;
      vq.v = *(const uint4*)(Tkqd + (size_t)qi * DIM + c8);
      vc.v = *(const uint4*)(Tkcd + (size_t)di * DIM + c8);
      const float4 k0 = *(const float4*)(Tkc + (size_t)ci * DIM + c8);
      const float4 k1 = *(const float4*)(Tkc + (size_t)ci * DIM + c8 + 4);
      float kk[8] = {k0.x, k0.y, k0.z, k0.w, k1.x, k1.y, k1.z, k1.w};
#pragma unroll
      for (int j = 0; j < 8; ++j) o.s[j] = f2b(kk[j] + b2f(vq.s[j]) + b2f(vc.s[j]));
      *(uint4*)&TS[row][c8] = o.v;
    }
  }
  __syncthreads();
  const int w = tid >> 6, L = tid & 63, q = L >> 4, m = L & 15;
  short8 wk[2][4];
#pragma unroll
  for (int T = 0; T < 2; ++T) {
    const int n = 32 * w + 16 * T + m;
#pragma unroll
    for (int kb = 0; kb < 4; ++kb) {
      const float* src = Wk + (size_t)n * 512 + kb * 32 + q * 8;
      const float4 v0 = *(const float4*)src;
      const float4 v1 = *(const float4*)(src + 4);
      short8 f;
      f[0] = (short)f2b(v0.x); f[1] = (short)f2b(v0.y);
      f[2] = (short)f2b(v0.z); f[3] = (short)f2b(v0.w);
      f[4] = (short)f2b(v1.x); f[5] = (short)f2b(v1.y);
      f[6] = (short)f2b(v1.z); f[7] = (short)f2b(v1.w);
      wk[T][kb] = f;
    }
  }
  const f32x4 vzero = {0.f, 0.f, 0.f, 0.f};
#pragma unroll
  for (int mt = 0; mt < 4; ++mt) {
    short8 af[4];
#pragma unroll
    for (int kb = 0; kb < 4; ++kb)
      af[kb] = *(const short8*)(xg + (size_t)(r0 + mt * 16 + m) * DIM + kb * 32 + q * 8);
    f32x4 acc[2] = {vzero, vzero};
#pragma unroll
    for (int kb = 0; kb < 4; ++kb) {
#pragma unroll
      for (int T = 0; T < 2; ++T)
        acc[T] = __builtin_amdgcn_mfma_f32_16x16x32_bf16(af[kb], wk[T][kb], acc[T], 0, 0, 0);
    }
#pragma unroll
    for (int T = 0; T < 2; ++T) {
      const int col = 32 * w + 16 * T + m;
#pragma unroll
      for (int i = 0; i < 4; ++i) {
        const int row64 = mt * 16 + q * 4 + i;
        GG[(size_t)(r0 + row64) * DIM + col] = f2b(acc[T][i] + b2f(TS[row64][col]));
      }
    }
  }
}

// ---------------- proj chunk (512 threads). 854 chunks:
// [0,782) Tq | [782,798) Tc | [798,800) Tqd | [800,802) Tcd |
// [802,853) Tkqd/Tkcd pairs | 853 Tkc
__device__ __forceinline__ void proj_chunk(
    const int j, const int tid,
    const float* Eq, const float* Ec, const float* Eqd, const float* Ecd,
    const float* Ecorr, const float* Wx, const float* Wk, const float* bk,
    unsigned short* Tq, unsigned short* Tc, unsigned short* Tqd, unsigned short* Tcd,
    float* Tkc, unsigned short* Tkqd, unsigned short* Tkcd,
    unsigned short (*A)[136]) {
  if (j < 802) {
    const float* E; int M, coff, r0; unsigned short* T;
    if (j < 782)      { E = Eq;  M = 50000; coff = 0;   T = Tq;  r0 = j * 64; }
    else if (j < 798) { E = Ec;  M = 1000;  coff = 128; T = Tc;  r0 = (j - 782) * 64; }
    else if (j < 800) { E = Eqd; M = 101;   coff = 256; T = Tqd; r0 = (j - 798) * 64; }
    else              { E = Ecd; M = 101;   coff = 384; T = Tcd; r0 = (j - 800) * 64; }
    {
      const int row = tid >> 3, c0 = (tid & 7) * 16;
      union U8 { uint4 v; unsigned short s[8]; } o;
#pragma unroll
      for (int cc = 0; cc < 2; ++cc) {
        const int c8 = c0 + cc * 8;
        if (r0 + row < M) {
          const float4 e0 = *(const float4*)(E + (size_t)(r0 + row) * DIM + c8);
          const float4 e1 = *(const float4*)(E + (size_t)(r0 + row) * DIM + c8 + 4);
          o.s[0] = f2b(e0.x); o.s[1] = f2b(e0.y); o.s[2] = f2b(e0.z); o.s[3] = f2b(e0.w);
          o.s[4] = f2b(e1.x); o.s[5] = f2b(e1.y); o.s[6] = f2b(e1.z); o.s[7] = f2b(e1.w);
        } else {
          o.v = make_uint4(0, 0, 0, 0);
        }
        *(uint4*)&A[row][c8] = o.v;
      }
    }
    __syncthreads();
    const int w = tid >> 6, L = tid & 63, q = L >> 4, m = L & 15;
    const int n = 16 * w + m;
    short8 bf[4];
#pragma unroll
    for (int kb = 0; kb < 4; ++kb) {
      const float* src = Wx + (size_t)n * 512 + coff + kb * 32 + q * 8;
      const float4 v0 = *(const float4*)src;
      const float4 v1 = *(const float4*)(src + 4);
      short8 f;
      f[0] = (short)f2b(v0.x); f[1] = (short)f2b(v0.y);
      f[2] = (short)f2b(v0.z); f[3] = (short)f2b(v0.w);
      f[4] = (short)f2b(v1.x); f[5] = (short)f2b(v1.y);
      f[6] = (short)f2b(v1.z); f[7] = (short)f2b(v1.w);
      bf[kb] = f;
    }
    const f32x4 vzero = {0.f, 0.f, 0.f, 0.f};
#pragma unroll
    for (int mt = 0; mt < 4; ++mt) {
      short8 af[4];
#pragma unroll
      for (int kb = 0; kb < 4; ++kb) af[kb] = *(const short8*)&A[mt * 16 + m][kb * 32 + q * 8];
      f32x4 acc = vzero;
#pragma unroll
      for (int kb = 0; kb < 4; ++kb)
        acc = __builtin_amdgcn_mfma_f32_16x16x32_bf16(af[kb], bf[kb], acc, 0, 0, 0);
#pragma unroll
      for (int i = 0; i < 4; ++i) {
        const int r = r0 + mt * 16 + q * 4 + i;
        if (r < M) T[(size_t)r * DIM + n] = f2b(acc[i]);
      }
    }
    __syncthreads();  // A reused by next chunk
  } else if (j < 853) {
    const int blk = 2 * (j - 802) + ((tid >> 8) & 1);
    const int o = tid & 127, half = (tid >> 7) & 1;
    if (blk < 101) {
      const float* e = (half ? Ecd : Eqd) + (size_t)blk * DIM;
      const float* wr = Wk + (size_t)o * 512 + (half ? 384 : 256);
      float a = 0.f;
      for (int k = 0; k < DIM; ++k) a = fmaf(e[k], wr[k], a);
      (half ? Tkcd : Tkqd)[blk * DIM + o] = f2b(a);
    }
  } else {
    if (tid < 256) {
      const int e2 = tid >> 7, o = tid & 127;
      const float* ec = Ecorr + e2 * DIM;
      const float* wr = Wk + (size_t)o * 512 + 128;
      float a = bk[o];
      for (int k = 0; k < DIM; ++k) a = fmaf(ec[k], wr[k], a);
      Tkc[e2 * DIM + o] = a;
    }
  }
}

// ---------------- producer item loop: per item (t,c): build 64 x-rows
// (X/SS/corrf) + table-sum TS in LDS, then MFMA vs Wk -> GG. 512 thr / 8 waves.
__device__ __forceinline__ void producer_body(
    const int p,
    const int* __restrict__ qs, const int* __restrict__ cs,
    const int* __restrict__ qds, const int* __restrict__ cds,
    const int* __restrict__ corr,
    const unsigned short* __restrict__ Tq, const unsigned short* __restrict__ Tc,
    const unsigned short* __restrict__ Tqd, const unsigned short* __restrict__ Tcd,
    const float* __restrict__ bx, const float* __restrict__ Wk,
    const float* __restrict__ Tkc, const unsigned short* __restrict__ Tkqd,
    const unsigned short* __restrict__ Tkcd,
    unsigned short* __restrict__ X, unsigned short* __restrict__ GG,
    float* __restrict__ SSg, float* __restrict__ corrf,
    int* donecnt, unsigned short (*xtile)[136], unsigned short (*TS)[136]) {
  const int tid = threadIdx.x;
  const int w = tid >> 6, L = tid & 63, q = L >> 4, m = L & 15;
  const int n = 16 * w + m;
  short8 wk[4];
#pragma unroll
  for (int kb = 0; kb < 4; ++kb) {
    const float* src = Wk + (size_t)n * 512 + kb * 32 + q * 8;
    const float4 v0 = *(const float4*)src;
    const float4 v1 = *(const float4*)(src + 4);
    short8 f;
    f[0] = (short)f2b(v0.x); f[1] = (short)f2b(v0.y);
    f[2] = (short)f2b(v0.z); f[3] = (short)f2b(v0.w);
    f[4] = (short)f2b(v1.x); f[5] = (short)f2b(v1.y);
    f[6] = (short)f2b(v1.z); f[7] = (short)f2b(v1.w);
    wk[kb] = f;
  }
  const int row = tid >> 3, k8 = tid & 7;
  const int c0 = k8 * 16;
  float bxv[16];
#pragma unroll
  for (int j = 0; j < 4; ++j) {
    const float4 bv = *(const float4*)(bx + c0 + j * 4);
    bxv[4 * j + 0] = bv.x; bxv[4 * j + 1] = bv.y;
    bxv[4 * j + 2] = bv.z; bxv[4 * j + 3] = bv.w;
  }
  const f32x4 vzero = {0.f, 0.f, 0.f, 0.f};
  union U8 { uint4 v; unsigned short s[8]; };

  for (int i = p; i < 3200; i += NPROD) {
    const int t = i >> 4, c = i & 15;
    const int b = c * 64 + row;
    const int base = b * S_LEN + t;
    const int qi = qs[base], ci = cs[base], qdi = qds[base], cdi = cds[base], cri = corr[base];
    float part = 0.f;
#pragma unroll
    for (int jj = 0; jj < 2; ++jj) {
      const int c8 = c0 + jj * 8;
      U8 vq, vc, vd, ve, o;
      vq.v = *(const uint4*)(Tq + (size_t)qi * DIM + c8);
      vc.v = *(const uint4*)(Tc + (size_t)ci * DIM + c8);
      vd.v = *(const uint4*)(Tqd + (size_t)qdi * DIM + c8);
      ve.v = *(const uint4*)(Tcd + (size_t)cdi * DIM + c8);
#pragma unroll
      for (int j = 0; j < 8; ++j) {
        const float sv = b2f(vq.s[j]) + b2f(vc.s[j]) + b2f(vd.s[j]) + b2f(ve.s[j]) + bxv[jj * 8 + j];
        o.s[j] = f2b(sv);
        const float xr = b2f(o.s[j]);
        part = fmaf(xr, xr, part);
      }
      *(uint4*)&xtile[row][c8] = o.v;
      *(uint4*)(X + (size_t)(t * 1024 + b) * DIM + c8) = o.v;
    }
#pragma unroll
    for (int off2 = 1; off2 <= 4; off2 <<= 1) part += __shfl_xor(part, off2, 64);
    if (k8 == 0) {
      SSg[t * 1024 + b] = part;
      corrf[t * 1024 + b] = (float)cri;
    }
    if (t < 199) {
#pragma unroll
      for (int jj = 0; jj < 2; ++jj) {
        const int c8 = c0 + jj * 8;
        U8 vq, vc, o;
        vq.v = *(const uint4*)(Tkqd + (size_t)qdi * DIM + c8);
        vc.v = *(const uint4*)(Tkcd + (size_t)cdi * DIM + c8);
        const float4 k0 = *(const float4*)(Tkc + (size_t)cri * DIM + c8);
        const float4 k1 = *(const float4*)(Tkc + (size_t)cri * DIM + c8 + 4);
        float kk[8] = {k0.x, k0.y, k0.z, k0.w, k1.x, k1.y, k1.z, k1.w};
#pragma unroll
        for (int j = 0; j < 8; ++j) o.s[j] = f2b(kk[j] + b2f(vq.s[j]) + b2f(vc.s[j]));
        *(uint4*)&TS[row][c8] = o.v;
      }
    }
    __syncthreads();
    if (t < 199) {
#pragma unroll
      for (int mt = 0; mt < 4; ++mt) {
        short8 af[4];
#pragma unroll
        for (int kb = 0; kb < 4; ++kb) af[kb] = *(const short8*)&xtile[mt * 16 + m][kb * 32 + q * 8];
        f32x4 acc = vzero;
#pragma unroll
        for (int kb = 0; kb < 4; ++kb)
          acc = __builtin_amdgcn_mfma_f32_16x16x32_bf16(af[kb], wk[kb], acc, 0, 0, 0);
#pragma unroll
        for (int i2 = 0; i2 < 4; ++i2) {
          const int row64 = mt * 16 + q * 4 + i2;
          GG[(size_t)(t * 1024 + c * 64 + row64) * DIM + n] = f2b(acc[i2] + b2f(TS[row64][n]));
        }
      }
    }
    __syncthreads();  // all stores drained (vmcnt(0) before s_barrier) + xtile reuse
    if (tid == 0)
      __hip_atomic_fetch_add(donecnt + t, 1, __ATOMIC_RELEASE, __HIP_MEMORY_SCOPE_AGENT);
  }
}

// ---------------- the recurrence (consumer). PIPE: R9's wm polling.
// Tp1c/Tp2c computed locally (bit-identical fmaf order to old proj_all).
template <bool PIPE>
__device__ __forceinline__ void scan_body(
    const unsigned short* __restrict__ xg, const unsigned short* __restrict__ gg,
    const float* __restrict__ SSg, const float* __restrict__ corrf,
    const float* __restrict__ h0,
    const float* __restrict__ Ws1, const float* __restrict__ bs1,
    const float* __restrict__ Ws2, const float* __restrict__ bs2,
    const float* __restrict__ Wp1, const float* __restrict__ bp1,
    const float* __restrict__ Wp2, const float* __restrict__ bp2,
    const float* __restrict__ Wk, const float* __restrict__ Ecorr,
    float* __restrict__ outp, int* wmp, unsigned short* ldsbase) {
  unsigned short (*Sbuf)[136] = (unsigned short (*)[136])ldsbase;
  unsigned short (*Pbuf)[136] = (unsigned short (*)[136])(ldsbase + 16 * 136);

  const int tid = threadIdx.x;
  const int w = tid >> 6, L = tid & 63, q = L >> 4, m = L & 15;
  const int col16 = 16 * w + m;
  const int rbase = blockIdx.x << 4;
  const size_t SB = (size_t)NBATCH * DIM;

  short8 wf[5][4];
  {
    const float* Wptr[5] = {Ws1, Ws2, Wp1, Wp2, Wk};
    const int ldw[5] = {128, 128, 256, 256, 512};
#pragma unroll
    for (int M = 0; M < 5; ++M) {
#pragma unroll
      for (int kb = 0; kb < 4; ++kb) {
        const float* src = Wptr[M] + (size_t)col16 * ldw[M] + kb * 32 + q * 8;
        const float4 v0 = *(const float4*)src;
        const float4 v1 = *(const float4*)(src + 4);
        short8 f;
        f[0] = (short)f2b(v0.x); f[1] = (short)f2b(v0.y);
        f[2] = (short)f2b(v0.z); f[3] = (short)f2b(v0.w);
        f[4] = (short)f2b(v1.x); f[5] = (short)f2b(v1.y);
        f[6] = (short)f2b(v1.z); f[7] = (short)f2b(v1.w);
        wf[M][kb] = f;
      }
    }
  }
  const float bs1v = bs1[col16], bs2v = bs2[col16];
  // local Tp1c/Tp2c (bit-identical fmaf order to the old proj_all small-table)
  float tp1v0, dtp1, tp2v0, dtp2;
  {
    float t10 = bp1[col16], t11 = t10;
    float t20 = bp2[col16], t21 = t20;
    const float* w1r = Wp1 + (size_t)col16 * 256 + 128;
    const float* w2r = Wp2 + (size_t)col16 * 256 + 128;
    for (int k = 0; k < DIM; k += 4) {
      const float4 a0 = *(const float4*)(Ecorr + k);
      const float4 a1 = *(const float4*)(Ecorr + DIM + k);
      const float4 b1 = *(const float4*)(w1r + k);
      const float4 b2 = *(const float4*)(w2r + k);
      t10 = fmaf(a0.x, b1.x, t10); t10 = fmaf(a0.y, b1.y, t10);
      t10 = fmaf(a0.z, b1.z, t10); t10 = fmaf(a0.w, b1.w, t10);
      t11 = fmaf(a1.x, b1.x, t11); t11 = fmaf(a1.y, b1.y, t11);
      t11 = fmaf(a1.z, b1.z, t11); t11 = fmaf(a1.w, b1.w, t11);
      t20 = fmaf(a0.x, b2.x, t20); t20 = fmaf(a0.y, b2.y, t20);
      t20 = fmaf(a0.z, b2.z, t20); t20 = fmaf(a0.w, b2.w, t20);
      t21 = fmaf(a1.x, b2.x, t21); t21 = fmaf(a1.y, b2.y, t21);
      t21 = fmaf(a1.z, b2.z, t21); t21 = fmaf(a1.w, b2.w, t21);
    }
    tp1v0 = t10; dtp1 = t11 - t10;
    tp2v0 = t20; dtp2 = t21 - t20;
  }
  if (tid < 16) outp[(size_t)(rbase + tid) * S_LEN + (S_LEN - 1)] = 0.0f;

  int wm_seen = 0;
  auto wait_wm = [&](int need) {
    if (wm_seen >= need) return;
    // relaxed polling (no per-poll cache-inv), one acquire load once satisfied
    while (__hip_atomic_load(wmp, __ATOMIC_RELAXED, __HIP_MEMORY_SCOPE_AGENT) < need)
      __builtin_amdgcn_s_sleep(8);
    wm_seen = __hip_atomic_load(wmp, __ATOMIC_ACQUIRE, __HIP_MEMORY_SCOPE_AGENT);
  };
  if (PIPE) wait_wm(3);  // prologue touches t = 0..2

  float h[4];
#pragma unroll
  for (int i = 0; i < 4; ++i) {
    const int b = rbase + q * 4 + i;
    const float hv = h0[(size_t)b * DIM + col16];
    h[i] = hv;
    const float xt = b2f(xg[(size_t)b * DIM + col16]);
    Sbuf[q * 4 + i][col16] = f2b(xt - hv);
  }
  float* poy = outp + (size_t)(rbase + m) * S_LEN;   // wave0 y stores, imm-offset t

  // distance-2 prefetch: register sets A/B + walking pointers (imm offsets)
  unsigned short XPA[4], XPB[4], GPA[4], GPB[4];
  float4 CFA, CFB;
  short8 XFA[4], XFB[4];
  float SSA, SSB;
  const unsigned short* pxA = xg + 3 * SB + (size_t)(rbase + q * 4) * DIM + col16;
  const unsigned short* pxB = pxA + SB;
  const unsigned short* pgA = gg + 2 * SB + (size_t)(rbase + q * 4) * DIM + col16;
  const unsigned short* pgB = pgA + SB;
  const float* pcA = corrf + 2 * NBATCH + rbase + q * 4;
  const float* pcB = pcA + NBATCH;
  const unsigned short* pfA = xg + 2 * SB + (size_t)(rbase + m) * DIM + q * 8;
  const unsigned short* pfB = pfA + SB;
  const float* psA = SSg + 2 * NBATCH + rbase + m;
  const float* psB = psA + NBATCH;
#pragma unroll
  for (int i = 0; i < 4; ++i) {
    XPA[i] = xg[SB + (size_t)(rbase + q * 4 + i) * DIM + col16];      // x[1]
    XPB[i] = xg[2 * SB + (size_t)(rbase + q * 4 + i) * DIM + col16];  // x[2]
    GPA[i] = gg[(size_t)(rbase + q * 4 + i) * DIM + col16];           // gg[0]
    GPB[i] = gg[SB + (size_t)(rbase + q * 4 + i) * DIM + col16];      // gg[1]
  }
  CFA = *(const float4*)(corrf + rbase + q * 4);
  CFB = *(const float4*)(corrf + NBATCH + rbase + q * 4);
#pragma unroll
  for (int kb = 0; kb < 4; ++kb) {
    XFA[kb] = *(const short8*)(xg + (size_t)(rbase + m) * DIM + kb * 32 + q * 8);        // x[0]
    XFB[kb] = *(const short8*)(xg + SB + (size_t)(rbase + m) * DIM + kb * 32 + q * 8);   // x[1]
  }
  SSA = SSg[rbase + m];
  SSB = SSg[NBATCH + rbase + m];

  const f32x4 vzero = {0.f, 0.f, 0.f, 0.f};

#define STEP(TCUR, XP, GP, CF, PX, PG, PC, XF, SSR, PF, PS)                    \
  do {                                                                         \
    const int t_ = (TCUR);                                                     \
    float xnv[4], ggv[4], cfv[4];                                              \
    _Pragma("unroll") for (int i = 0; i < 4; ++i) {                            \
      xnv[i] = b2f(XP[i]); ggv[i] = b2f(GP[i]);                                \
    }                                                                          \
    cfv[0] = CF.x; cfv[1] = CF.y; cfv[2] = CF.z; cfv[3] = CF.w;                \
    short8 xfr[4]; float ssv = SSR;                                            \
    if (w == 0) {                                                              \
      _Pragma("unroll") for (int kb = 0; kb < 4; ++kb) xfr[kb] = XF[kb];       \
    }                                                                          \
    _Pragma("unroll") for (int i = 0; i < 4; ++i) {                            \
      XP[i] = PX[i * DIM]; GP[i] = PG[i * DIM];                                \
    }                                                                          \
    CF = *(const float4*)PC;                                                   \
    PX += 2 * SB; PG += 2 * SB; PC += 2 * NBATCH;                              \
    if (w == 0) {                                                              \
      _Pragma("unroll") for (int kb = 0; kb < 4; ++kb)                         \
        XF[kb] = *(const short8*)(PF + kb * 32);                               \
      SSR = *PS;                                                               \
      PF += 2 * SB; PS += 2 * NBATCH;                                          \
    }                                                                          \
    wg_barrier_lds(); /* Sbuf(t) ready */                                      \
    short8 sf[4];                                                              \
    _Pragma("unroll") for (int kb = 0; kb < 4; ++kb)                           \
        sf[kb] = *(const short8*)&Sbuf[m][kb * 32 + q * 8];                    \
    f32x4 a1 = vzero, a2 = vzero, c1 = vzero;                                  \
    _Pragma("unroll") for (int kb = 0; kb < 4; ++kb) {                         \
      a1 = __builtin_amdgcn_mfma_f32_16x16x32_bf16(sf[kb], wf[0][kb], a1, 0, 0, 0); \
      a2 = __builtin_amdgcn_mfma_f32_16x16x32_bf16(sf[kb], wf[1][kb], a2, 0, 0, 0); \
      c1 = __builtin_amdgcn_mfma_f32_16x16x32_bf16(sf[kb], wf[4][kb], c1, 0, 0, 0); \
    }                                                                          \
    if (w == 0) {                                                              \
      f32x4 dt = vzero;                                                        \
      _Pragma("unroll") for (int kb = 0; kb < 4; ++kb)                         \
        dt = __builtin_amdgcn_mfma_f32_16x16x32_bf16(sf[kb], xfr[kb], dt, 0, 0, 0); \
      if (t_ > 0 && q == (m >> 2)) {                                           \
        const int ii = m & 3;                                                  \
        const float D = ii == 0 ? dt[0] : ii == 1 ? dt[1] : ii == 2 ? dt[2] : dt[3]; \
        poy[t_ - 1] = fast_sigmoid(ssv - D);                                   \
      }                                                                        \
    }                                                                          \
    _Pragma("unroll") for (int i2 = 0; i2 < 2; ++i2) {                         \
      const float s0 = fast_sigmoid(a1[2 * i2] + bs1v) * fast_tanh(a2[2 * i2] + bs2v); \
      const float s1 = fast_sigmoid(a1[2 * i2 + 1] + bs1v) * fast_tanh(a2[2 * i2 + 1] + bs2v); \
      const unsigned u = pk_bf16(s0, s1);                                      \
      Pbuf[q * 4 + 2 * i2][col16] = (unsigned short)u;                         \
      Pbuf[q * 4 + 2 * i2 + 1][col16] = (unsigned short)(u >> 16);             \
    }                                                                          \
    wg_barrier_lds(); /* Pbuf ready */                                         \
    short8 pf[4];                                                              \
    _Pragma("unroll") for (int kb = 0; kb < 4; ++kb)                           \
        pf[kb] = *(const short8*)&Pbuf[m][kb * 32 + q * 8];                    \
    f32x4 p1 = vzero, p2 = vzero;                                              \
    _Pragma("unroll") for (int kb = 0; kb < 4; ++kb) {                         \
      p1 = __builtin_amdgcn_mfma_f32_16x16x32_bf16(pf[kb], wf[2][kb], p1, 0, 0, 0); \
      p2 = __builtin_amdgcn_mfma_f32_16x16x32_bf16(pf[kb], wf[3][kb], p2, 0, 0, 0); \
    }                                                                          \
    float sn[4];                                                               \
    _Pragma("unroll") for (int i = 0; i < 4; ++i) {                            \
      const float g = fast_sigmoid(ggv[i] - c1[i]);                            \
      const float t1v = fmaf(cfv[i], dtp1, tp1v0);                             \
      const float t2v = fmaf(cfv[i], dtp2, tp2v0);                             \
      const float pka = fast_sigmoid(p1[i] + t1v) * fast_tanh(p2[i] + t2v);    \
      const float hn = pka + g * (h[i] - pka);                                 \
      h[i] = hn;                                                               \
      sn[i] = xnv[i] - hn;                                                     \
    }                                                                          \
    _Pragma("unroll") for (int i2 = 0; i2 < 2; ++i2) {                         \
      const unsigned u = pk_bf16(sn[2 * i2], sn[2 * i2 + 1]);                  \
      Sbuf[q * 4 + 2 * i2][col16] = (unsigned short)u;                         \
      Sbuf[q * 4 + 2 * i2 + 1][col16] = (unsigned short)(u >> 16);             \
    }                                                                          \
  } while (0)

  for (int t2 = 0; t2 < 198; t2 += 2) {
    if (PIPE) {  // pair (t2,t2+1) prefetches up to t2+4
      const int need = (t2 + 5 > 200) ? 200 : t2 + 5;
      wait_wm(need);
    }
    STEP(t2, XPA, GPA, CFA, pxA, pgA, pcA, XFA, SSA, pfA, psA);
    STEP(t2 + 1, XPB, GPB, CFB, pxB, pgB, pcB, XFB, SSB, pfB, psB);
  }
  STEP(198, XPA, GPA, CFA, pxA, pgA, pcA, XFA, SSA, pfA, psA);
#undef STEP

  // epilogue: y(198) from s(199) in Sbuf, x[199] (= XFB), ss[199] (= SSB)
  wg_barrier_lds();
  if (w == 0) {
    short8 sf[4];
#pragma unroll
    for (int kb = 0; kb < 4; ++kb) sf[kb] = *(const short8*)&Sbuf[m][kb * 32 + q * 8];
    f32x4 dt = vzero;
#pragma unroll
    for (int kb = 0; kb < 4; ++kb)
      dt = __builtin_amdgcn_mfma_f32_16x16x32_bf16(sf[kb], XFB[kb], dt, 0, 0, 0);
    if (q == (m >> 2)) {
      const int ii = m & 3;
      const float D = ii == 0 ? dt[0] : ii == 1 ? dt[1] : ii == 2 ? dt[2] : dt[3];
      poy[S_LEN - 2] = fast_sigmoid(SSB - D);
    }
  }
}

// ---------------- fused kernel. PIPE: all blocks proj first, then
// [0,64) scan | [64,255) producers (gated on projdone==256) | 255 sweeper.
template <bool PIPE>
__global__ __launch_bounds__(512, 2) void scan_fused_kernel(
    const unsigned short* xg, const unsigned short* gg,
    const float* SSg, const float* corrf, const float* h0,
    const float* Ws1, const float* bs1, const float* Ws2, const float* bs2,
    const float* Wp1, const float* bp1, const float* Wp2, const float* bp2,
    const float* WkF, const float* Ecorr, float* outp,
    const int* qs, const int* cs, const int* qds, const int* cds, const int* corr,
    unsigned short* Tq, unsigned short* Tc, unsigned short* Tqd, unsigned short* Tcd,
    const float* bx, float* Tkc, unsigned short* Tkqd, unsigned short* Tkcd,
    const float* Eq, const float* Ec, const float* Eqd, const float* Ecd,
    const float* Wx, const float* bk,
    unsigned short* Xw, unsigned short* GGw, float* SSw, float* corrw,
    int* donecnt, int* wmp, int* projdone) {
  __shared__ __align__(16) unsigned short lds[PIPE ? 2 * 64 * 136 : 2 * 16 * 136];
  const int bid = blockIdx.x, tid = threadIdx.x;
  if constexpr (PIPE) {
    // phase 0: ALL 256 blocks run proj chunks (max parallelism)
    for (int j = bid; j < NCHUNK; j += NBLK)
      proj_chunk(j, tid, Eq, Ec, Eqd, Ecd, Ecorr, Wx, WkF, bk,
                 Tq, Tc, Tqd, Tcd, Tkc, Tkqd, Tkcd, (unsigned short (*)[136])lds);
    __syncthreads();  // drain this block's proj stores (vmcnt 0 before barrier)
    if (tid == 0)
      __hip_atomic_fetch_add(projdone, 1, __ATOMIC_RELEASE, __HIP_MEMORY_SCOPE_AGENT);
    if (bid >= 64) {
      if (bid == 255) {
        // wave-parallel sweep: 64 lanes poll donecnt[base..+63] coalesced,
        // ballot the contiguous done-prefix, publish wm once per round.
        if (tid < 64) {
          const int lane = tid;
          int base = 0;
          while (base < S_LEN) {
            const int t = base + lane;
            const int v = (t < S_LEN)
                ? __hip_atomic_load(donecnt + t, __ATOMIC_RELAXED, __HIP_MEMORY_SCOPE_AGENT)
                : 16;
            const unsigned long long ball = __ballot(v >= 16);
            const unsigned long long nb = ~ball;
            int adv = nb ? (__ffsll((unsigned long long)nb) - 1) : 64;
            if (adv > S_LEN - base) adv = S_LEN - base;
            if (adv > 0) {
              if (lane == 0) {
                (void)__hip_atomic_load(donecnt + base + adv - 1, __ATOMIC_ACQUIRE,
                                        __HIP_MEMORY_SCOPE_AGENT);
                __hip_atomic_store(wmp, base + adv, __ATOMIC_RELEASE,
                                   __HIP_MEMORY_SCOPE_AGENT);
              }
              base += adv;
            } else {
              __builtin_amdgcn_s_sleep(2);
            }
          }
        }
        return;
      }
      // producers: wait for ALL proj chunks (ONE poller per block, no storm)
      if (tid == 0) {
        while (__hip_atomic_load(projdone, __ATOMIC_RELAXED, __HIP_MEMORY_SCOPE_AGENT) < NBLK)
          __builtin_amdgcn_s_sleep(4);
        (void)__hip_atomic_load(projdone, __ATOMIC_ACQUIRE, __HIP_MEMORY_SCOPE_AGENT);
      }
      __syncthreads();
      producer_body(bid - 64, qs, cs, qds, cds, corr, Tq, Tc, Tqd, Tcd, bx,
                    WkF, Tkc, Tkqd, Tkcd, Xw, GGw, SSw, corrw, donecnt,
                    (unsigned short (*)[136])lds,
                    (unsigned short (*)[136])(lds + 64 * 136));
      return;
    }
  }
  scan_body<PIPE>(xg, gg, SSg, corrf, h0, Ws1, bs1, Ws2, bs2, Wp1, bp1, Wp2, bp2,
                  WkF, Ecorr, outp, wmp, lds);
}

extern "C" void kernel_launch(void* const* d_in, const int* in_sizes, int n_in,
                              void* d_out, int out_size, void* d_ws, size_t ws_size,
                              hipStream_t stream) {
  const int* qs    = (const int*)d_in[0];
  const int* cs    = (const int*)d_in[1];
  const int* qds   = (const int*)d_in[2];
  const int* cds   = (const int*)d_in[3];
  const int* corr  = (const int*)d_in[4];
  const float* Eq    = (const float*)d_in[5];
  const float* Ec    = (const float*)d_in[6];
  const float* Eqd   = (const float*)d_in[7];
  const float* Ecd   = (const float*)d_in[8];
  const float* Ecorr = (const float*)d_in[9];
  const float* Wx  = (const float*)d_in[10];
  const float* bx  = (const float*)d_in[11];
  const float* Ws1 = (const float*)d_in[12];
  const float* bs1 = (const float*)d_in[13];
  const float* Ws2 = (const float*)d_in[14];
  const float* bs2 = (const float*)d_in[15];
  const float* Wp1 = (const float*)d_in[16];
  const float* bp1 = (const float*)d_in[17];
  const float* Wp2 = (const float*)d_in[18];
  const float* bp2 = (const float*)d_in[19];
  const float* Wk  = (const float*)d_in[20];
  const float* bk  = (const float*)d_in[21];
  const float* h0  = (const float*)d_in[22];

  char* ws = (char*)d_ws;
  const size_t xbytes = (size_t)S_LEN * NBATCH * DIM * 2;
  const size_t ggbytes = (size_t)(S_LEN - 1) * NBATCH * DIM * 2;

  // ---- fused (non-aliased) layout: X | GG | corrf | SS | tables | sync.
  // Prefetch overruns (<=2 steps past X/GG/corrf/SS ends) land in the next
  // region -- harmless garbage reads inside d_ws, never consumed.
  {
    size_t off = 0;
    auto alloc = [&](size_t bytes) {
      void* p = ws + off;
      off = (off + bytes + 255) & ~(size_t)255;
      return p;
    };
    unsigned short* X  = (unsigned short*)alloc(xbytes);
    unsigned short* GG = (unsigned short*)alloc(ggbytes);
    float* corrf = (float*)alloc((size_t)S_LEN * NBATCH * 4);
    float* SS    = (float*)alloc((size_t)S_LEN * NBATCH * 4);
    unsigned short* Tq  = (unsigned short*)alloc((size_t)50000 * DIM * 2);
    unsigned short* Tc  = (unsigned short*)alloc((size_t)1000 * DIM * 2);
    unsigned short* Tqd = (unsigned short*)alloc((size_t)101 * DIM * 2);
    unsigned short* Tcd = (unsigned short*)alloc((size_t)101 * DIM * 2);
    unsigned short* Tkqd = (unsigned short*)alloc((size_t)101 * DIM * 2);
    unsigned short* Tkcd = (unsigned short*)alloc((size_t)101 * DIM * 2);
    float* Tkc  = (float*)alloc((size_t)2 * DIM * 4);
    int* syncz  = (int*)alloc(2048);   // donecnt[0..199] | wm@256 | projdone@272
    if (off <= ws_size) {
      zero_sync_kernel<<<1, 512, 0, stream>>>(syncz);
      scan_fused_kernel<true><<<256, 512, 0, stream>>>(
          X, GG, SS, corrf, h0, Ws1, bs1, Ws2, bs2, Wp1, bp1, Wp2, bp2, Wk, Ecorr,
          (float*)d_out, qs, cs, qds, cds, corr, Tq, Tc, Tqd, Tcd, bx,
          Tkc, Tkqd, Tkcd, Eq, Ec, Eqd, Ecd, Wx, bk,
          X, GG, SS, corrf, syncz, syncz + 256, syncz + 272);
      return;
    }
  }

  // ---- fallback: original 4-kernel path (GG aliases Tq..Tcd during build)
  const size_t A = (xbytes + 255) & ~(size_t)255;
  unsigned short* X  = (unsigned short*)ws;
  unsigned short* GG = (unsigned short*)(ws + A);
  unsigned short* Tq  = GG;  // alias (dead after build_x)
  unsigned short* Tc  = (unsigned short*)(ws + A + (size_t)50000 * DIM * 2);
  unsigned short* Tqd = (unsigned short*)(ws + A + (size_t)51000 * DIM * 2);
  unsigned short* Tcd = (unsigned short*)(ws + A + (size_t)51101 * DIM * 2);
  size_t off = A + ((ggbytes + 255) & ~(size_t)255);
  auto alloc = [&](size_t bytes) {
    void* p = ws + off;
    off = (off + bytes + 255) & ~(size_t)255;
    return p;
  };
  float* corrf = (float*)alloc((size_t)S_LEN * NBATCH * 4);
  float* SS    = (float*)alloc((size_t)S_LEN * NBATCH * 4);
  unsigned short* Tkqd = (unsigned short*)alloc((size_t)101 * DIM * 2);
  unsigned short* Tkcd = (unsigned short*)alloc((size_t)101 * DIM * 2);
  float* Tkc  = (float*)alloc((size_t)2 * DIM * 4);
  int* syncz  = (int*)alloc(2048);

  proj_all_kernel<<<904, 256, 0, stream>>>(Eq, Ec, Eqd, Ecd, Ecorr, Wx,
                                           Wp1, bp1, Wp2, bp2, Wk, bk,
                                           Tq, Tc, Tqd, Tcd, Tkqd, Tkcd, Tkc);
  build_x_kernel<<<(S_LEN * NBATCH) / 16, 256, 0, stream>>>(qs, cs, qds, cds, corr,
                                                            Tq, Tc, Tqd, Tcd, bx, X, SS, corrf);
  gemm_xg_kernel<<<((S_LEN - 1) * NBATCH) / 64, 256, 0, stream>>>(X, Wk, corr, qds, cds,
                                                                  Tkc, Tkqd, Tkcd, GG);
  scan_fused_kernel<false><<<64, 512, 0, stream>>>(
      X, GG, SS, corrf, h0, Ws1, bs1, Ws2, bs2, Wp1, bp1, Wp2, bp2, Wk, Ecorr,
      (float*)d_out, qs, cs, qds, cds, corr, Tq, Tc, Tqd, Tcd, bx,
      Tkc, Tkqd, Tkcd, Eq, Ec, Eqd, Ecd, Wx, bk,
      X, GG, SS, corrf, syncz, syncz + 256, syncz + 272);
}

// Round 5
// 468.299 us; speedup vs baseline: 1.0668x; 1.0668x over previous
//
#include <hip/hip_runtime.h>
#include <hip/hip_bf16.h>

// DIMKT: B=1024, S=200, D=128.
// R11: R9 structure (proven best: 343us fused / 458.6 total) + ONE change:
// XCD-partitioned role mapping in the fused kernel. Default bid%8 round-robin
// interleaves 8 scan blocks + 24 producers per XCD L2; producer streaming
// (~230MB in the first ~90us) thrashes the scan's L2. Now scan = bids with
// bid%8<2 (XCDs 0-1 exclusively), producers+sweeper = bid%8>=2 (XCDs 2-7).
// R10's proj merge (fused 343->425) reverted; proj_all separate again.

#define S_LEN 200
#define NBATCH 1024
#define DIM 128
#define LOG2E 1.4426950408889634f
#define NPROD 191

typedef short short8 __attribute__((ext_vector_type(8)));
typedef float f32x4 __attribute__((ext_vector_type(4)));

__device__ __forceinline__ unsigned short f2b(float f) {
  union { float f; unsigned u; } v; v.f = f;
  unsigned r = (v.u + 0x7FFFu + ((v.u >> 16) & 1u)) >> 16;  // RNE
  return (unsigned short)r;
}
__device__ __forceinline__ float b2f(unsigned short b) {
  union { unsigned u; float f; } v; v.u = ((unsigned)b) << 16;
  return v.f;
}
__device__ __forceinline__ unsigned pk_bf16(float lo, float hi) {
  __hip_bfloat162 t = __float22bfloat162_rn(make_float2(lo, hi));
  union { __hip_bfloat162 h; unsigned u; } cv; cv.h = t;
  return cv.u;
}
__device__ __forceinline__ float fast_sigmoid(float x) {
  return __builtin_amdgcn_rcpf(1.0f + __builtin_amdgcn_exp2f(-LOG2E * x));
}
__device__ __forceinline__ float fast_tanh(float x) {
  return 2.0f * __builtin_amdgcn_rcpf(1.0f + __builtin_amdgcn_exp2f(-2.0f * LOG2E * x)) - 1.0f;
}
// LDS-only barrier: does NOT drain vmcnt, prefetches stay in flight.
__device__ __forceinline__ void wg_barrier_lds() {
  __asm__ volatile("s_waitcnt lgkmcnt(0)\n\ts_barrier" ::: "memory");
}

// ---------------- P1: projected embedding tables via MFMA, 64 rows/block.
// blocks: [0,782) Tq | [782,798) Tc | [798,800) Tqd | [800,802) Tcd | [802,904) small
__global__ void proj_all_kernel(const float* __restrict__ Eq, const float* __restrict__ Ec,
                                const float* __restrict__ Eqd, const float* __restrict__ Ecd,
                                const float* __restrict__ Ecorr,
                                const float* __restrict__ Wx,
                                const float* __restrict__ Wp1, const float* __restrict__ bp1,
                                const float* __restrict__ Wp2, const float* __restrict__ bp2,
                                const float* __restrict__ Wk, const float* __restrict__ bk,
                                unsigned short* __restrict__ Tq, unsigned short* __restrict__ Tc,
                                unsigned short* __restrict__ Tqd, unsigned short* __restrict__ Tcd,
                                unsigned short* __restrict__ Tkqd, unsigned short* __restrict__ Tkcd,
                                float* __restrict__ Tkc, float* __restrict__ Tp1c,
                                float* __restrict__ Tp2c, int* __restrict__ syncz) {
  const int bid = blockIdx.x;
  const int tid = threadIdx.x;
  if (bid >= 802) {
    const int blk = bid - 802;
    if (blk < 101) {
      const int o = tid & 127, half = tid >> 7;
      const float* e = (half ? Ecd : Eqd) + (size_t)blk * DIM;
      const float* wr = Wk + (size_t)o * 512 + (half ? 384 : 256);
      float a = 0.f;
      for (int k = 0; k < DIM; ++k) a = fmaf(e[k], wr[k], a);
      (half ? Tkcd : Tkqd)[blk * DIM + o] = f2b(a);
    } else {
      for (int idx = tid; idx < 768; idx += 256) {
        const int t = idx >> 8, e = (idx >> 7) & 1, o = idx & 127;
        const float* ec = Ecorr + e * DIM;
        const float* wr; float bias; float* dst;
        if (t == 0)      { wr = Wp1 + (size_t)o * 256 + 128; bias = bp1[o]; dst = Tp1c; }
        else if (t == 1) { wr = Wp2 + (size_t)o * 256 + 128; bias = bp2[o]; dst = Tp2c; }
        else             { wr = Wk  + (size_t)o * 512 + 128; bias = bk[o];  dst = Tkc;  }
        float a = bias;
        for (int k = 0; k < DIM; ++k) a = fmaf(ec[k], wr[k], a);
        dst[e * DIM + o] = a;
      }
      // zero the producer/consumer sync area (donecnt[256] + wm) each iteration
      for (int i2 = tid; i2 < 272; i2 += 256) syncz[i2] = 0;
    }
    return;
  }
  const float* E; int M, coff, r0; unsigned short* T;
  if (bid < 782)      { E = Eq;  M = 50000; coff = 0;   T = Tq;  r0 = bid * 64; }
  else if (bid < 798) { E = Ec;  M = 1000;  coff = 128; T = Tc;  r0 = (bid - 782) * 64; }
  else if (bid < 800) { E = Eqd; M = 101;   coff = 256; T = Tqd; r0 = (bid - 798) * 64; }
  else                { E = Ecd; M = 101;   coff = 384; T = Tcd; r0 = (bid - 800) * 64; }

  __shared__ __align__(16) unsigned short A[64][136];
  {
    const int row = tid >> 2, cb = (tid & 3) * 32;
    union U8 { uint4 v; unsigned short s[8]; } o;
#pragma unroll
    for (int cc = 0; cc < 4; ++cc) {
      const int c8 = cb + cc * 8;
      if (r0 + row < M) {
        const float4 e0 = *(const float4*)(E + (size_t)(r0 + row) * DIM + c8);
        const float4 e1 = *(const float4*)(E + (size_t)(r0 + row) * DIM + c8 + 4);
        o.s[0] = f2b(e0.x); o.s[1] = f2b(e0.y); o.s[2] = f2b(e0.z); o.s[3] = f2b(e0.w);
        o.s[4] = f2b(e1.x); o.s[5] = f2b(e1.y); o.s[6] = f2b(e1.z); o.s[7] = f2b(e1.w);
      } else {
        o.v = make_uint4(0, 0, 0, 0);
      }
      *(uint4*)&A[row][c8] = o.v;
    }
  }
  __syncthreads();
  const int w = tid >> 6, L = tid & 63, q = L >> 4, m = L & 15;
  short8 bf[2][4];
#pragma unroll
  for (int T2 = 0; T2 < 2; ++T2) {
    const int n = 32 * w + 16 * T2 + m;
#pragma unroll
    for (int kb = 0; kb < 4; ++kb) {
      const float* src = Wx + (size_t)n * 512 + coff + kb * 32 + q * 8;
      const float4 v0 = *(const float4*)src;
      const float4 v1 = *(const float4*)(src + 4);
      short8 f;
      f[0] = (short)f2b(v0.x); f[1] = (short)f2b(v0.y);
      f[2] = (short)f2b(v0.z); f[3] = (short)f2b(v0.w);
      f[4] = (short)f2b(v1.x); f[5] = (short)f2b(v1.y);
      f[6] = (short)f2b(v1.z); f[7] = (short)f2b(v1.w);
      bf[T2][kb] = f;
    }
  }
  const f32x4 vzero = {0.f, 0.f, 0.f, 0.f};
#pragma unroll
  for (int mt = 0; mt < 4; ++mt) {
    short8 af[4];
#pragma unroll
    for (int kb = 0; kb < 4; ++kb) af[kb] = *(const short8*)&A[mt * 16 + m][kb * 32 + q * 8];
    f32x4 acc[2] = {vzero, vzero};
#pragma unroll
    for (int kb = 0; kb < 4; ++kb) {
#pragma unroll
      for (int T2 = 0; T2 < 2; ++T2)
        acc[T2] = __builtin_amdgcn_mfma_f32_16x16x32_bf16(af[kb], bf[T2][kb], acc[T2], 0, 0, 0);
    }
#pragma unroll
    for (int T2 = 0; T2 < 2; ++T2) {
      const int col = 32 * w + 16 * T2 + m;
#pragma unroll
      for (int i = 0; i < 4; ++i) {
        const int r = r0 + mt * 16 + q * 4 + i;
        if (r < M) T[(size_t)r * DIM + col] = f2b(acc[T2][i]);
      }
    }
  }
}

// ---------------- P2 (fallback only): x build
__global__ void build_x_kernel(const int* __restrict__ qs, const int* __restrict__ cs,
                               const int* __restrict__ qds, const int* __restrict__ cds,
                               const int* __restrict__ corr,
                               const unsigned short* __restrict__ Tq, const unsigned short* __restrict__ Tc,
                               const unsigned short* __restrict__ Tqd, const unsigned short* __restrict__ Tcd,
                               const float* __restrict__ bx, unsigned short* __restrict__ xg,
                               float* __restrict__ SSg, float* __restrict__ corrf) {
  const int r = blockIdx.x * 16 + (threadIdx.x >> 4);   // r = s*1024 + b
  const int c8 = (threadIdx.x & 15) * 8;
  const int s = r >> 10, b = r & 1023;
  const int q = qs[b * S_LEN + s], c = cs[b * S_LEN + s];
  const int qd = qds[b * S_LEN + s], cd = cds[b * S_LEN + s];
  union U8 { uint4 v; unsigned short s[8]; };
  U8 vq, vc, vd, ve, o;
  vq.v = *(const uint4*)(Tq + (size_t)q * DIM + c8);
  vc.v = *(const uint4*)(Tc + (size_t)c * DIM + c8);
  vd.v = *(const uint4*)(Tqd + (size_t)qd * DIM + c8);
  ve.v = *(const uint4*)(Tcd + (size_t)cd * DIM + c8);
  const float4 bx0 = *(const float4*)(bx + c8);
  const float4 bx1 = *(const float4*)(bx + c8 + 4);
  float bb[8] = {bx0.x, bx0.y, bx0.z, bx0.w, bx1.x, bx1.y, bx1.z, bx1.w};
  float part = 0.f;
#pragma unroll
  for (int j = 0; j < 8; ++j) {
    const float sv = b2f(vq.s[j]) + b2f(vc.s[j]) + b2f(vd.s[j]) + b2f(ve.s[j]) + bb[j];
    o.s[j] = f2b(sv);
    const float xr = b2f(o.s[j]);
    part = fmaf(xr, xr, part);
  }
  *(uint4*)(xg + (size_t)r * DIM + c8) = o.v;
#pragma unroll
  for (int off = 1; off <= 8; off <<= 1) part += __shfl_xor(part, off, 64);
  if ((threadIdx.x & 15) == 0) {
    SSg[r] = part;
    corrf[r] = (float)corr[b * S_LEN + s];
  }
}

// ---------------- P3 (fallback only): GG gemm
__global__ void gemm_xg_kernel(const unsigned short* __restrict__ xg,
                               const float* __restrict__ Wk,
                               const int* __restrict__ corr, const int* __restrict__ qds,
                               const int* __restrict__ cds,
                               const float* __restrict__ Tkc,
                               const unsigned short* __restrict__ Tkqd,
                               const unsigned short* __restrict__ Tkcd,
                               unsigned short* __restrict__ GG) {
  const int tid = threadIdx.x;
  const int r0 = blockIdx.x * 64;   // r = t*1024 + b, t <= 198
  __shared__ __align__(16) unsigned short TS[64][136];
  {
    const int row = tid >> 2, cb = (tid & 3) * 32;
    const int r = r0 + row, t = r >> 10, b = r & 1023;
    const int ci = corr[b * S_LEN + t], qi = qds[b * S_LEN + t], di = cds[b * S_LEN + t];
    union U8 { uint4 v; unsigned short s[8]; };
#pragma unroll
    for (int cc = 0; cc < 4; ++cc) {
      const int c8 = cb + cc * 8;
      U8 vq, vc, o;
      vq.v = *(const uint4*)(Tkqd + (size_t)qi * DIM + c8);
      vc.v = *(const uint4*)(Tkcd + (size_t)di * DIM + c8);
      const float4 k0 = *(const float4*)(Tkc + (size_t)ci * DIM + c8);
      const float4 k1 = *(const float4*)(Tkc + (size_t)ci * DIM + c8 + 4);
      float kk[8] = {k0.x, k0.y, k0.z, k0.w, k1.x, k1.y, k1.z, k1.w};
#pragma unroll
      for (int j = 0; j < 8; ++j) o.s[j] = f2b(kk[j] + b2f(vq.s[j]) + b2f(vc.s[j]));
      *(uint4*)&TS[row][c8] = o.v;
    }
  }
  __syncthreads();
  const int w = tid >> 6, L = tid & 63, q = L >> 4, m = L & 15;
  short8 wk[2][4];
#pragma unroll
  for (int T = 0; T < 2; ++T) {
    const int n = 32 * w + 16 * T + m;
#pragma unroll
    for (int kb = 0; kb < 4; ++kb) {
      const float* src = Wk + (size_t)n * 512 + kb * 32 + q * 8;
      const float4 v0 = *(const float4*)src;
      const float4 v1 = *(const float4*)(src + 4);
      short8 f;
      f[0] = (short)f2b(v0.x); f[1] = (short)f2b(v0.y);
      f[2] = (short)f2b(v0.z); f[3] = (short)f2b(v0.w);
      f[4] = (short)f2b(v1.x); f[5] = (short)f2b(v1.y);
      f[6] = (short)f2b(v1.z); f[7] = (short)f2b(v1.w);
      wk[T][kb] = f;
    }
  }
  const f32x4 vzero = {0.f, 0.f, 0.f, 0.f};
#pragma unroll
  for (int mt = 0; mt < 4; ++mt) {
    short8 af[4];
#pragma unroll
    for (int kb = 0; kb < 4; ++kb)
      af[kb] = *(const short8*)(xg + (size_t)(r0 + mt * 16 + m) * DIM + kb * 32 + q * 8);
    f32x4 acc[2] = {vzero, vzero};
#pragma unroll
    for (int kb = 0; kb < 4; ++kb) {
#pragma unroll
      for (int T = 0; T < 2; ++T)
        acc[T] = __builtin_amdgcn_mfma_f32_16x16x32_bf16(af[kb], wk[T][kb], acc[T], 0, 0, 0);
    }
#pragma unroll
    for (int T = 0; T < 2; ++T) {
      const int col = 32 * w + 16 * T + m;
#pragma unroll
      for (int i = 0; i < 4; ++i) {
        const int row64 = mt * 16 + q * 4 + i;
        GG[(size_t)(r0 + row64) * DIM + col] = f2b(acc[T][i] + b2f(TS[row64][col]));
      }
    }
  }
}

// ---------------- producer body: per item (t,c): build 64 x-rows (X/SS/corrf)
// + table-sum TS in LDS, then MFMA them against Wk -> GG. 512 thr / 8 waves.
__device__ __forceinline__ void producer_body(
    const int p,
    const int* __restrict__ qs, const int* __restrict__ cs,
    const int* __restrict__ qds, const int* __restrict__ cds,
    const int* __restrict__ corr,
    const unsigned short* __restrict__ Tq, const unsigned short* __restrict__ Tc,
    const unsigned short* __restrict__ Tqd, const unsigned short* __restrict__ Tcd,
    const float* __restrict__ bx, const float* __restrict__ Wk,
    const float* __restrict__ Tkc, const unsigned short* __restrict__ Tkqd,
    const unsigned short* __restrict__ Tkcd,
    unsigned short* __restrict__ X, unsigned short* __restrict__ GG,
    float* __restrict__ SSg, float* __restrict__ corrf,
    int* donecnt, unsigned short (*xtile)[136], unsigned short (*TS)[136]) {
  const int tid = threadIdx.x;
  const int w = tid >> 6, L = tid & 63, q = L >> 4, m = L & 15;
  const int n = 16 * w + m;
  short8 wk[4];
#pragma unroll
  for (int kb = 0; kb < 4; ++kb) {
    const float* src = Wk + (size_t)n * 512 + kb * 32 + q * 8;
    const float4 v0 = *(const float4*)src;
    const float4 v1 = *(const float4*)(src + 4);
    short8 f;
    f[0] = (short)f2b(v0.x); f[1] = (short)f2b(v0.y);
    f[2] = (short)f2b(v0.z); f[3] = (short)f2b(v0.w);
    f[4] = (short)f2b(v1.x); f[5] = (short)f2b(v1.y);
    f[6] = (short)f2b(v1.z); f[7] = (short)f2b(v1.w);
    wk[kb] = f;
  }
  const int row = tid >> 3, k8 = tid & 7;
  const int c0 = k8 * 16;
  float bxv[16];
#pragma unroll
  for (int j = 0; j < 4; ++j) {
    const float4 bv = *(const float4*)(bx + c0 + j * 4);
    bxv[4 * j + 0] = bv.x; bxv[4 * j + 1] = bv.y;
    bxv[4 * j + 2] = bv.z; bxv[4 * j + 3] = bv.w;
  }
  const f32x4 vzero = {0.f, 0.f, 0.f, 0.f};
  union U8 { uint4 v; unsigned short s[8]; };

  for (int i = p; i < 3200; i += NPROD) {
    const int t = i >> 4, c = i & 15;
    const int b = c * 64 + row;
    const int base = b * S_LEN + t;
    const int qi = qs[base], ci = cs[base], qdi = qds[base], cdi = cds[base], cri = corr[base];
    float part = 0.f;
#pragma unroll
    for (int jj = 0; jj < 2; ++jj) {
      const int c8 = c0 + jj * 8;
      U8 vq, vc, vd, ve, o;
      vq.v = *(const uint4*)(Tq + (size_t)qi * DIM + c8);
      vc.v = *(const uint4*)(Tc + (size_t)ci * DIM + c8);
      vd.v = *(const uint4*)(Tqd + (size_t)qdi * DIM + c8);
      ve.v = *(const uint4*)(Tcd + (size_t)cdi * DIM + c8);
#pragma unroll
      for (int j = 0; j < 8; ++j) {
        const float sv = b2f(vq.s[j]) + b2f(vc.s[j]) + b2f(vd.s[j]) + b2f(ve.s[j]) + bxv[jj * 8 + j];
        o.s[j] = f2b(sv);
        const float xr = b2f(o.s[j]);
        part = fmaf(xr, xr, part);
      }
      *(uint4*)&xtile[row][c8] = o.v;
      *(uint4*)(X + (size_t)(t * 1024 + b) * DIM + c8) = o.v;
    }
#pragma unroll
    for (int off2 = 1; off2 <= 4; off2 <<= 1) part += __shfl_xor(part, off2, 64);
    if (k8 == 0) {
      SSg[t * 1024 + b] = part;
      corrf[t * 1024 + b] = (float)cri;
    }
    if (t < 199) {
#pragma unroll
      for (int jj = 0; jj < 2; ++jj) {
        const int c8 = c0 + jj * 8;
        U8 vq, vc, o;
        vq.v = *(const uint4*)(Tkqd + (size_t)qdi * DIM + c8);
        vc.v = *(const uint4*)(Tkcd + (size_t)cdi * DIM + c8);
        const float4 k0 = *(const float4*)(Tkc + (size_t)cri * DIM + c8);
        const float4 k1 = *(const float4*)(Tkc + (size_t)cri * DIM + c8 + 4);
        float kk[8] = {k0.x, k0.y, k0.z, k0.w, k1.x, k1.y, k1.z, k1.w};
#pragma unroll
        for (int j = 0; j < 8; ++j) o.s[j] = f2b(kk[j] + b2f(vq.s[j]) + b2f(vc.s[j]));
        *(uint4*)&TS[row][c8] = o.v;
      }
    }
    __syncthreads();
    if (t < 199) {
#pragma unroll
      for (int mt = 0; mt < 4; ++mt) {
        short8 af[4];
#pragma unroll
        for (int kb = 0; kb < 4; ++kb) af[kb] = *(const short8*)&xtile[mt * 16 + m][kb * 32 + q * 8];
        f32x4 acc = vzero;
#pragma unroll
        for (int kb = 0; kb < 4; ++kb)
          acc = __builtin_amdgcn_mfma_f32_16x16x32_bf16(af[kb], wk[kb], acc, 0, 0, 0);
#pragma unroll
        for (int i2 = 0; i2 < 4; ++i2) {
          const int row64 = mt * 16 + q * 4 + i2;
          GG[(size_t)(t * 1024 + c * 64 + row64) * DIM + n] = f2b(acc[i2] + b2f(TS[row64][n]));
        }
      }
    }
    __syncthreads();  // all stores drained (vmcnt(0) before s_barrier) + xtile reuse
    if (tid == 0)
      __hip_atomic_fetch_add(donecnt + t, 1, __ATOMIC_RELEASE, __HIP_MEMORY_SCOPE_AGENT);
  }
}

// ---------------- the recurrence (consumer). Identical math to R6 scan_kernel;
// PIPE adds watermark waits before prefetch issue.
template <bool PIPE>
__device__ __forceinline__ void scan_body(
    const int rbase,
    const unsigned short* __restrict__ xg, const unsigned short* __restrict__ gg,
    const float* __restrict__ SSg, const float* __restrict__ corrf,
    const float* __restrict__ h0,
    const float* __restrict__ Ws1, const float* __restrict__ bs1,
    const float* __restrict__ Ws2, const float* __restrict__ bs2,
    const float* __restrict__ Wp1, const float* __restrict__ Wp2,
    const float* __restrict__ Wk,
    const float* __restrict__ gTp1c, const float* __restrict__ gTp2c,
    float* __restrict__ outp, int* wmp, unsigned short* ldsbase) {
  unsigned short (*Sbuf)[136] = (unsigned short (*)[136])ldsbase;
  unsigned short (*Pbuf)[136] = (unsigned short (*)[136])(ldsbase + 16 * 136);

  const int tid = threadIdx.x;
  const int w = tid >> 6, L = tid & 63, q = L >> 4, m = L & 15;
  const int col16 = 16 * w + m;
  const size_t SB = (size_t)NBATCH * DIM;

  short8 wf[5][4];
  {
    const float* Wptr[5] = {Ws1, Ws2, Wp1, Wp2, Wk};
    const int ldw[5] = {128, 128, 256, 256, 512};
#pragma unroll
    for (int M = 0; M < 5; ++M) {
#pragma unroll
      for (int kb = 0; kb < 4; ++kb) {
        const float* src = Wptr[M] + (size_t)col16 * ldw[M] + kb * 32 + q * 8;
        const float4 v0 = *(const float4*)src;
        const float4 v1 = *(const float4*)(src + 4);
        short8 f;
        f[0] = (short)f2b(v0.x); f[1] = (short)f2b(v0.y);
        f[2] = (short)f2b(v0.z); f[3] = (short)f2b(v0.w);
        f[4] = (short)f2b(v1.x); f[5] = (short)f2b(v1.y);
        f[6] = (short)f2b(v1.z); f[7] = (short)f2b(v1.w);
        wf[M][kb] = f;
      }
    }
  }
  const float bs1v = bs1[col16], bs2v = bs2[col16];
  const float tp1v0 = gTp1c[col16], dtp1 = gTp1c[DIM + col16] - tp1v0;
  const float tp2v0 = gTp2c[col16], dtp2 = gTp2c[DIM + col16] - tp2v0;
  if (tid < 16) outp[(size_t)(rbase + tid) * S_LEN + (S_LEN - 1)] = 0.0f;

  int wm_seen = 0;
  auto wait_wm = [&](int need) {
    if (wm_seen >= need) return;
    // relaxed polling (no per-poll cache-inv), one acquire load once satisfied
    while (__hip_atomic_load(wmp, __ATOMIC_RELAXED, __HIP_MEMORY_SCOPE_AGENT) < need)
      __builtin_amdgcn_s_sleep(8);
    wm_seen = __hip_atomic_load(wmp, __ATOMIC_ACQUIRE, __HIP_MEMORY_SCOPE_AGENT);
  };
  if (PIPE) wait_wm(3);  // prologue touches t = 0..2

  float h[4];
#pragma unroll
  for (int i = 0; i < 4; ++i) {
    const int b = rbase + q * 4 + i;
    const float hv = h0[(size_t)b * DIM + col16];
    h[i] = hv;
    const float xt = b2f(xg[(size_t)b * DIM + col16]);
    Sbuf[q * 4 + i][col16] = f2b(xt - hv);
  }
  float* poy = outp + (size_t)(rbase + m) * S_LEN;   // wave0 y stores, imm-offset t

  // distance-2 prefetch: register sets A/B + walking pointers (imm offsets)
  unsigned short XPA[4], XPB[4], GPA[4], GPB[4];
  float4 CFA, CFB;
  short8 XFA[4], XFB[4];
  float SSA, SSB;
  const unsigned short* pxA = xg + 3 * SB + (size_t)(rbase + q * 4) * DIM + col16;
  const unsigned short* pxB = pxA + SB;
  const unsigned short* pgA = gg + 2 * SB + (size_t)(rbase + q * 4) * DIM + col16;
  const unsigned short* pgB = pgA + SB;
  const float* pcA = corrf + 2 * NBATCH + rbase + q * 4;
  const float* pcB = pcA + NBATCH;
  const unsigned short* pfA = xg + 2 * SB + (size_t)(rbase + m) * DIM + q * 8;
  const unsigned short* pfB = pfA + SB;
  const float* psA = SSg + 2 * NBATCH + rbase + m;
  const float* psB = psA + NBATCH;
#pragma unroll
  for (int i = 0; i < 4; ++i) {
    XPA[i] = xg[SB + (size_t)(rbase + q * 4 + i) * DIM + col16];      // x[1]
    XPB[i] = xg[2 * SB + (size_t)(rbase + q * 4 + i) * DIM + col16];  // x[2]
    GPA[i] = gg[(size_t)(rbase + q * 4 + i) * DIM + col16];           // gg[0]
    GPB[i] = gg[SB + (size_t)(rbase + q * 4 + i) * DIM + col16];      // gg[1]
  }
  CFA = *(const float4*)(corrf + rbase + q * 4);
  CFB = *(const float4*)(corrf + NBATCH + rbase + q * 4);
#pragma unroll
  for (int kb = 0; kb < 4; ++kb) {
    XFA[kb] = *(const short8*)(xg + (size_t)(rbase + m) * DIM + kb * 32 + q * 8);        // x[0]
    XFB[kb] = *(const short8*)(xg + SB + (size_t)(rbase + m) * DIM + kb * 32 + q * 8);   // x[1]
  }
  SSA = SSg[rbase + m];
  SSB = SSg[NBATCH + rbase + m];

  const f32x4 vzero = {0.f, 0.f, 0.f, 0.f};

#define STEP(TCUR, XP, GP, CF, PX, PG, PC, XF, SSR, PF, PS)                    \
  do {                                                                         \
    const int t_ = (TCUR);                                                     \
    float xnv[4], ggv[4], cfv[4];                                              \
    _Pragma("unroll") for (int i = 0; i < 4; ++i) {                            \
      xnv[i] = b2f(XP[i]); ggv[i] = b2f(GP[i]);                                \
    }                                                                          \
    cfv[0] = CF.x; cfv[1] = CF.y; cfv[2] = CF.z; cfv[3] = CF.w;                \
    short8 xfr[4]; float ssv = SSR;                                            \
    if (w == 0) {                                                              \
      _Pragma("unroll") for (int kb = 0; kb < 4; ++kb) xfr[kb] = XF[kb];       \
    }                                                                          \
    _Pragma("unroll") for (int i = 0; i < 4; ++i) {                            \
      XP[i] = PX[i * DIM]; GP[i] = PG[i * DIM];                                \
    }                                                                          \
    CF = *(const float4*)PC;                                                   \
    PX += 2 * SB; PG += 2 * SB; PC += 2 * NBATCH;                              \
    if (w == 0) {                                                              \
      _Pragma("unroll") for (int kb = 0; kb < 4; ++kb)                         \
        XF[kb] = *(const short8*)(PF + kb * 32);                               \
      SSR = *PS;                                                               \
      PF += 2 * SB; PS += 2 * NBATCH;                                          \
    }                                                                          \
    wg_barrier_lds(); /* Sbuf(t) ready */                                      \
    short8 sf[4];                                                              \
    _Pragma("unroll") for (int kb = 0; kb < 4; ++kb)                           \
        sf[kb] = *(const short8*)&Sbuf[m][kb * 32 + q * 8];                    \
    f32x4 a1 = vzero, a2 = vzero, c1 = vzero;                                  \
    _Pragma("unroll") for (int kb = 0; kb < 4; ++kb) {                         \
      a1 = __builtin_amdgcn_mfma_f32_16x16x32_bf16(sf[kb], wf[0][kb], a1, 0, 0, 0); \
      a2 = __builtin_amdgcn_mfma_f32_16x16x32_bf16(sf[kb], wf[1][kb], a2, 0, 0, 0); \
      c1 = __builtin_amdgcn_mfma_f32_16x16x32_bf16(sf[kb], wf[4][kb], c1, 0, 0, 0); \
    }                                                                          \
    if (w == 0) {                                                              \
      f32x4 dt = vzero;                                                        \
      _Pragma("unroll") for (int kb = 0; kb < 4; ++kb)                         \
        dt = __builtin_amdgcn_mfma_f32_16x16x32_bf16(sf[kb], xfr[kb], dt, 0, 0, 0); \
      if (t_ > 0 && q == (m >> 2)) {                                           \
        const int ii = m & 3;                                                  \
        const float D = ii == 0 ? dt[0] : ii == 1 ? dt[1] : ii == 2 ? dt[2] : dt[3]; \
        poy[t_ - 1] = fast_sigmoid(ssv - D);                                   \
      }                                                                        \
    }                                                                          \
    _Pragma("unroll") for (int i2 = 0; i2 < 2; ++i2) {                         \
      const float s0 = fast_sigmoid(a1[2 * i2] + bs1v) * fast_tanh(a2[2 * i2] + bs2v); \
      const float s1 = fast_sigmoid(a1[2 * i2 + 1] + bs1v) * fast_tanh(a2[2 * i2 + 1] + bs2v); \
      const unsigned u = pk_bf16(s0, s1);                                      \
      Pbuf[q * 4 + 2 * i2][col16] = (unsigned short)u;                         \
      Pbuf[q * 4 + 2 * i2 + 1][col16] = (unsigned short)(u >> 16);             \
    }                                                                          \
    wg_barrier_lds(); /* Pbuf ready */                                         \
    short8 pf[4];                                                              \
    _Pragma("unroll") for (int kb = 0; kb < 4; ++kb)                           \
        pf[kb] = *(const short8*)&Pbuf[m][kb * 32 + q * 8];                    \
    f32x4 p1 = vzero, p2 = vzero;                                              \
    _Pragma("unroll") for (int kb = 0; kb < 4; ++kb) {                         \
      p1 = __builtin_amdgcn_mfma_f32_16x16x32_bf16(pf[kb], wf[2][kb], p1, 0, 0, 0); \
      p2 = __builtin_amdgcn_mfma_f32_16x16x32_bf16(pf[kb], wf[3][kb], p2, 0, 0, 0); \
    }                                                                          \
    float sn[4];                                                               \
    _Pragma("unroll") for (int i = 0; i < 4; ++i) {                            \
      const float g = fast_sigmoid(ggv[i] - c1[i]);                            \
      const float t1v = fmaf(cfv[i], dtp1, tp1v0);                             \
      const float t2v = fmaf(cfv[i], dtp2, tp2v0);                             \
      const float pka = fast_sigmoid(p1[i] + t1v) * fast_tanh(p2[i] + t2v);    \
      const float hn = pka + g * (h[i] - pka);                                 \
      h[i] = hn;                                                               \
      sn[i] = xnv[i] - hn;                                                     \
    }                                                                          \
    _Pragma("unroll") for (int i2 = 0; i2 < 2; ++i2) {                         \
      const unsigned u = pk_bf16(sn[2 * i2], sn[2 * i2 + 1]);                  \
      Sbuf[q * 4 + 2 * i2][col16] = (unsigned short)u;                         \
      Sbuf[q * 4 + 2 * i2 + 1][col16] = (unsigned short)(u >> 16);             \
    }                                                                          \
  } while (0)

  for (int t2 = 0; t2 < 198; t2 += 2) {
    if (PIPE) {  // pair (t2,t2+1) prefetches up to t2+4
      const int need = (t2 + 5 > 200) ? 200 : t2 + 5;
      wait_wm(need);
    }
    STEP(t2, XPA, GPA, CFA, pxA, pgA, pcA, XFA, SSA, pfA, psA);
    STEP(t2 + 1, XPB, GPB, CFB, pxB, pgB, pcB, XFB, SSB, pfB, psB);
  }
  STEP(198, XPA, GPA, CFA, pxA, pgA, pcA, XFA, SSA, pfA, psA);
#undef STEP

  // epilogue: y(198) from s(199) in Sbuf, x[199] (= XFB), ss[199] (= SSB)
  wg_barrier_lds();
  if (w == 0) {
    short8 sf[4];
#pragma unroll
    for (int kb = 0; kb < 4; ++kb) sf[kb] = *(const short8*)&Sbuf[m][kb * 32 + q * 8];
    f32x4 dt = vzero;
#pragma unroll
    for (int kb = 0; kb < 4; ++kb)
      dt = __builtin_amdgcn_mfma_f32_16x16x32_bf16(sf[kb], XFB[kb], dt, 0, 0, 0);
    if (q == (m >> 2)) {
      const int ii = m & 3;
      const float D = ii == 0 ? dt[0] : ii == 1 ? dt[1] : ii == 2 ? dt[2] : dt[3];
      poy[S_LEN - 2] = fast_sigmoid(SSB - D);
    }
  }
}

// ---------------- fused kernel, XCD-partitioned roles (PIPE):
// bid%8 < 2  -> scan block   (XCDs 0-1; scan_idx = (bid>>3)*2 + (bid&7))
// bid%8 >= 2 -> producer     (XCDs 2-7; prod_idx = (bid>>3)*6 + (bid&7)-2)
//               prod_idx==191 (bid==255) is the wave-parallel sweeper.
template <bool PIPE>
__global__ __launch_bounds__(512, 2) void scan_fused_kernel(
    const unsigned short* __restrict__ xg, const unsigned short* __restrict__ gg,
    const float* __restrict__ SSg, const float* __restrict__ corrf,
    const float* __restrict__ h0,
    const float* __restrict__ Ws1, const float* __restrict__ bs1,
    const float* __restrict__ Ws2, const float* __restrict__ bs2,
    const float* __restrict__ Wp1, const float* __restrict__ Wp2,
    const float* __restrict__ WkF,
    const float* __restrict__ gTp1c, const float* __restrict__ gTp2c,
    float* __restrict__ outp,
    const int* __restrict__ qs, const int* __restrict__ cs,
    const int* __restrict__ qds, const int* __restrict__ cds,
    const int* __restrict__ corr,
    const unsigned short* __restrict__ Tq, const unsigned short* __restrict__ Tc,
    const unsigned short* __restrict__ Tqd, const unsigned short* __restrict__ Tcd,
    const float* __restrict__ bx, const float* __restrict__ Tkc,
    const unsigned short* __restrict__ Tkqd, const unsigned short* __restrict__ Tkcd,
    unsigned short* __restrict__ Xw, unsigned short* __restrict__ GGw,
    float* __restrict__ SSw, float* __restrict__ corrw,
    int* donecnt, int* wmp) {
  __shared__ __align__(16) unsigned short lds[PIPE ? 2 * 64 * 136 : 2 * 16 * 136];
  const int bid = blockIdx.x;
  if (!PIPE) {
    scan_body<false>(bid << 4, xg, gg, SSg, corrf, h0, Ws1, bs1, Ws2, bs2,
                     Wp1, Wp2, WkF, gTp1c, gTp2c, outp, wmp, lds);
    return;
  }
  if constexpr (PIPE) {
    const int mod = bid & 7;
    if (mod < 2) {
      const int scan_idx = (bid >> 3) * 2 + mod;     // [0,64) on XCDs 0-1
      scan_body<true>(scan_idx << 4, xg, gg, SSg, corrf, h0, Ws1, bs1, Ws2, bs2,
                      Wp1, Wp2, WkF, gTp1c, gTp2c, outp, wmp, lds);
      return;
    }
    const int prod_idx = (bid >> 3) * 6 + (mod - 2);  // [0,192) on XCDs 2-7
    if (prod_idx == NPROD) {
      // wave-parallel sweep: 64 lanes poll donecnt[base..base+63] (coalesced),
      // ballot the contiguous done-prefix, publish wm once per round.
      if (threadIdx.x < 64) {
        const int lane = threadIdx.x;
        int base = 0;
        while (base < S_LEN) {
          const int t = base + lane;
          const int v = (t < S_LEN)
              ? __hip_atomic_load(donecnt + t, __ATOMIC_RELAXED, __HIP_MEMORY_SCOPE_AGENT)
              : 16;
          const unsigned long long ball = __ballot(v >= 16);
          const unsigned long long nb = ~ball;
          int adv = nb ? (__ffsll((unsigned long long)nb) - 1) : 64;
          if (adv > S_LEN - base) adv = S_LEN - base;
          if (adv > 0) {
            if (lane == 0) {
              (void)__hip_atomic_load(donecnt + base + adv - 1, __ATOMIC_ACQUIRE,
                                      __HIP_MEMORY_SCOPE_AGENT);
              __hip_atomic_store(wmp, base + adv, __ATOMIC_RELEASE,
                                 __HIP_MEMORY_SCOPE_AGENT);
            }
            base += adv;
          } else {
            __builtin_amdgcn_s_sleep(2);
          }
        }
      }
      return;
    }
    producer_body(prod_idx, qs, cs, qds, cds, corr, Tq, Tc, Tqd, Tcd, bx,
                  WkF, Tkc, Tkqd, Tkcd, Xw, GGw, SSw, corrw, donecnt,
                  (unsigned short (*)[136])lds,
                  (unsigned short (*)[136])(lds + 64 * 136));
  }
}

extern "C" void kernel_launch(void* const* d_in, const int* in_sizes, int n_in,
                              void* d_out, int out_size, void* d_ws, size_t ws_size,
                              hipStream_t stream) {
  const int* qs    = (const int*)d_in[0];
  const int* cs    = (const int*)d_in[1];
  const int* qds   = (const int*)d_in[2];
  const int* cds   = (const int*)d_in[3];
  const int* corr  = (const int*)d_in[4];
  const float* Eq    = (const float*)d_in[5];
  const float* Ec    = (const float*)d_in[6];
  const float* Eqd   = (const float*)d_in[7];
  const float* Ecd   = (const float*)d_in[8];
  const float* Ecorr = (const float*)d_in[9];
  const float* Wx  = (const float*)d_in[10];
  const float* bx  = (const float*)d_in[11];
  const float* Ws1 = (const float*)d_in[12];
  const float* bs1 = (const float*)d_in[13];
  const float* Ws2 = (const float*)d_in[14];
  const float* bs2 = (const float*)d_in[15];
  const float* Wp1 = (const float*)d_in[16];
  const float* bp1 = (const float*)d_in[17];
  const float* Wp2 = (const float*)d_in[18];
  const float* bp2 = (const float*)d_in[19];
  const float* Wk  = (const float*)d_in[20];
  const float* bk  = (const float*)d_in[21];
  const float* h0  = (const float*)d_in[22];

  char* ws = (char*)d_ws;
  const size_t xbytes = (size_t)S_LEN * NBATCH * DIM * 2;
  const size_t ggbytes = (size_t)(S_LEN - 1) * NBATCH * DIM * 2;

  // ---- fused (non-aliased) layout: X | GG | corrf | SS | tables | sync.
  // Prefetch overruns (<=2 steps past X/GG/corrf/SS ends) land in the next
  // region -- harmless garbage reads inside d_ws, never consumed.
  {
    size_t off = 0;
    auto alloc = [&](size_t bytes) {
      void* p = ws + off;
      off = (off + bytes + 255) & ~(size_t)255;
      return p;
    };
    unsigned short* X  = (unsigned short*)alloc(xbytes);
    unsigned short* GG = (unsigned short*)alloc(ggbytes);
    float* corrf = (float*)alloc((size_t)S_LEN * NBATCH * 4);
    float* SS    = (float*)alloc((size_t)S_LEN * NBATCH * 4);
    unsigned short* Tq  = (unsigned short*)alloc((size_t)50000 * DIM * 2);
    unsigned short* Tc  = (unsigned short*)alloc((size_t)1000 * DIM * 2);
    unsigned short* Tqd = (unsigned short*)alloc((size_t)101 * DIM * 2);
    unsigned short* Tcd = (unsigned short*)alloc((size_t)101 * DIM * 2);
    unsigned short* Tkqd = (unsigned short*)alloc((size_t)101 * DIM * 2);
    unsigned short* Tkcd = (unsigned short*)alloc((size_t)101 * DIM * 2);
    float* Tkc  = (float*)alloc((size_t)2 * DIM * 4);
    float* Tp1c = (float*)alloc((size_t)2 * DIM * 4);
    float* Tp2c = (float*)alloc((size_t)2 * DIM * 4);
    int* syncz  = (int*)alloc(2048);   // donecnt[256] + wm
    if (off <= ws_size) {
      proj_all_kernel<<<904, 256, 0, stream>>>(Eq, Ec, Eqd, Ecd, Ecorr, Wx,
                                               Wp1, bp1, Wp2, bp2, Wk, bk,
                                               Tq, Tc, Tqd, Tcd, Tkqd, Tkcd,
                                               Tkc, Tp1c, Tp2c, syncz);
      scan_fused_kernel<true><<<256, 512, 0, stream>>>(
          X, GG, SS, corrf, h0, Ws1, bs1, Ws2, bs2, Wp1, Wp2, Wk, Tp1c, Tp2c,
          (float*)d_out, qs, cs, qds, cds, corr, Tq, Tc, Tqd, Tcd, bx,
          Tkc, Tkqd, Tkcd, X, GG, SS, corrf, syncz, syncz + 256);
      return;
    }
  }

  // ---- fallback: original 4-kernel path (GG aliases Tq..Tcd during build)
  const size_t A = (xbytes + 255) & ~(size_t)255;
  unsigned short* X  = (unsigned short*)ws;
  unsigned short* GG = (unsigned short*)(ws + A);
  unsigned short* Tq  = GG;  // alias (dead after build_x)
  unsigned short* Tc  = (unsigned short*)(ws + A + (size_t)50000 * DIM * 2);
  unsigned short* Tqd = (unsigned short*)(ws + A + (size_t)51000 * DIM * 2);
  unsigned short* Tcd = (unsigned short*)(ws + A + (size_t)51101 * DIM * 2);
  size_t off = A + ((ggbytes + 255) & ~(size_t)255);
  auto alloc = [&](size_t bytes) {
    void* p = ws + off;
    off = (off + bytes + 255) & ~(size_t)255;
    return p;
  };
  float* corrf = (float*)alloc((size_t)S_LEN * NBATCH * 4);
  float* SS    = (float*)alloc((size_t)S_LEN * NBATCH * 4);
  unsigned short* Tkqd = (unsigned short*)alloc((size_t)101 * DIM * 2);
  unsigned short* Tkcd = (unsigned short*)alloc((size_t)101 * DIM * 2);
  float* Tkc  = (float*)alloc((size_t)2 * DIM * 4);
  float* Tp1c = (float*)alloc((size_t)2 * DIM * 4);
  float* Tp2c = (float*)alloc((size_t)2 * DIM * 4);
  int* syncz  = (int*)alloc(2048);

  proj_all_kernel<<<904, 256, 0, stream>>>(Eq, Ec, Eqd, Ecd, Ecorr, Wx,
                                           Wp1, bp1, Wp2, bp2, Wk, bk,
                                           Tq, Tc, Tqd, Tcd, Tkqd, Tkcd, Tkc, Tp1c, Tp2c,
                                           syncz);
  build_x_kernel<<<(S_LEN * NBATCH) / 16, 256, 0, stream>>>(qs, cs, qds, cds, corr,
                                                            Tq, Tc, Tqd, Tcd, bx, X, SS, corrf);
  gemm_xg_kernel<<<((S_LEN - 1) * NBATCH) / 64, 256, 0, stream>>>(X, Wk, corr, qds, cds,
                                                                  Tkc, Tkqd, Tkcd, GG);
  scan_fused_kernel<false><<<64, 512, 0, stream>>>(
      X, GG, SS, corrf, h0, Ws1, bs1, Ws2, bs2, Wp1, Wp2, Wk, Tp1c, Tp2c,
      (float*)d_out, qs, cs, qds, cds, corr, Tq, Tc, Tqd, Tcd, bx,
      Tkc, Tkqd, Tkcd, X, GG, SS, corrf, syncz, syncz + 256);
}

// Round 6
// 448.767 us; speedup vs baseline: 1.1132x; 1.0435x over previous
//
#include <hip/hip_runtime.h>
#include <hip/hip_bf16.h>

// DIMKT: B=1024, S=200, D=128.
// R12: revert to R9 (proven best: 343us fused / 458.6 total; R11's XCD
// partition hurt, 373/468) + proj_all tiling: 4 x 64-row tiles per block,
// Wx bf-fragments loaded ONCE per block (was re-read by each of 782 Tq
// blocks = 48MB redundant L2/L3 traffic), grid 904 -> 304. Bit-identical
// math (fragment load hoisted, per-tile op order unchanged).

#define S_LEN 200
#define NBATCH 1024
#define DIM 128
#define LOG2E 1.4426950408889634f
#define NPROD 191

typedef short short8 __attribute__((ext_vector_type(8)));
typedef float f32x4 __attribute__((ext_vector_type(4)));

__device__ __forceinline__ unsigned short f2b(float f) {
  union { float f; unsigned u; } v; v.f = f;
  unsigned r = (v.u + 0x7FFFu + ((v.u >> 16) & 1u)) >> 16;  // RNE
  return (unsigned short)r;
}
__device__ __forceinline__ float b2f(unsigned short b) {
  union { unsigned u; float f; } v; v.u = ((unsigned)b) << 16;
  return v.f;
}
__device__ __forceinline__ unsigned pk_bf16(float lo, float hi) {
  __hip_bfloat162 t = __float22bfloat162_rn(make_float2(lo, hi));
  union { __hip_bfloat162 h; unsigned u; } cv; cv.h = t;
  return cv.u;
}
__device__ __forceinline__ float fast_sigmoid(float x) {
  return __builtin_amdgcn_rcpf(1.0f + __builtin_amdgcn_exp2f(-LOG2E * x));
}
__device__ __forceinline__ float fast_tanh(float x) {
  return 2.0f * __builtin_amdgcn_rcpf(1.0f + __builtin_amdgcn_exp2f(-2.0f * LOG2E * x)) - 1.0f;
}
// LDS-only barrier: does NOT drain vmcnt, prefetches stay in flight.
__device__ __forceinline__ void wg_barrier_lds() {
  __asm__ volatile("s_waitcnt lgkmcnt(0)\n\ts_barrier" ::: "memory");
}

// ---------------- P1: projected embedding tables via MFMA.
// 4 x 64-row tiles per block; Wx fragments loaded once per block.
// blocks: [0,196) Tq | [196,200) Tc | [200,201) Tqd | [201,202) Tcd |
//         [202,303) Tkqd/Tkcd pairs | 303 combo (Tp1c/Tp2c/Tkc + syncz)
__global__ void proj_all_kernel(const float* __restrict__ Eq, const float* __restrict__ Ec,
                                const float* __restrict__ Eqd, const float* __restrict__ Ecd,
                                const float* __restrict__ Ecorr,
                                const float* __restrict__ Wx,
                                const float* __restrict__ Wp1, const float* __restrict__ bp1,
                                const float* __restrict__ Wp2, const float* __restrict__ bp2,
                                const float* __restrict__ Wk, const float* __restrict__ bk,
                                unsigned short* __restrict__ Tq, unsigned short* __restrict__ Tc,
                                unsigned short* __restrict__ Tqd, unsigned short* __restrict__ Tcd,
                                unsigned short* __restrict__ Tkqd, unsigned short* __restrict__ Tkcd,
                                float* __restrict__ Tkc, float* __restrict__ Tp1c,
                                float* __restrict__ Tp2c, int* __restrict__ syncz) {
  const int bid = blockIdx.x;
  const int tid = threadIdx.x;
  if (bid >= 202) {
    const int blk = bid - 202;
    if (blk < 101) {
      const int o = tid & 127, half = tid >> 7;
      const float* e = (half ? Ecd : Eqd) + (size_t)blk * DIM;
      const float* wr = Wk + (size_t)o * 512 + (half ? 384 : 256);
      float a = 0.f;
      for (int k = 0; k < DIM; ++k) a = fmaf(e[k], wr[k], a);
      (half ? Tkcd : Tkqd)[blk * DIM + o] = f2b(a);
    } else {
      for (int idx = tid; idx < 768; idx += 256) {
        const int t = idx >> 8, e = (idx >> 7) & 1, o = idx & 127;
        const float* ec = Ecorr + e * DIM;
        const float* wr; float bias; float* dst;
        if (t == 0)      { wr = Wp1 + (size_t)o * 256 + 128; bias = bp1[o]; dst = Tp1c; }
        else if (t == 1) { wr = Wp2 + (size_t)o * 256 + 128; bias = bp2[o]; dst = Tp2c; }
        else             { wr = Wk  + (size_t)o * 512 + 128; bias = bk[o];  dst = Tkc;  }
        float a = bias;
        for (int k = 0; k < DIM; ++k) a = fmaf(ec[k], wr[k], a);
        dst[e * DIM + o] = a;
      }
      // zero the producer/consumer sync area (donecnt[256] + wm) each iteration
      for (int i2 = tid; i2 < 272; i2 += 256) syncz[i2] = 0;
    }
    return;
  }
  const float* E; int M, coff, t0; unsigned short* T;
  if (bid < 196)      { E = Eq;  M = 50000; coff = 0;   T = Tq;  t0 = bid * 4; }
  else if (bid < 200) { E = Ec;  M = 1000;  coff = 128; T = Tc;  t0 = (bid - 196) * 4; }
  else if (bid < 201) { E = Eqd; M = 101;   coff = 256; T = Tqd; t0 = 0; }
  else                { E = Ecd; M = 101;   coff = 384; T = Tcd; t0 = 0; }

  __shared__ __align__(16) unsigned short A[64][136];
  const int w = tid >> 6, L = tid & 63, q = L >> 4, m = L & 15;
  // Wx fragments: loaded ONCE per block (coff fixed), reused for all tiles.
  short8 bf[2][4];
#pragma unroll
  for (int T2 = 0; T2 < 2; ++T2) {
    const int n = 32 * w + 16 * T2 + m;
#pragma unroll
    for (int kb = 0; kb < 4; ++kb) {
      const float* src = Wx + (size_t)n * 512 + coff + kb * 32 + q * 8;
      const float4 v0 = *(const float4*)src;
      const float4 v1 = *(const float4*)(src + 4);
      short8 f;
      f[0] = (short)f2b(v0.x); f[1] = (short)f2b(v0.y);
      f[2] = (short)f2b(v0.z); f[3] = (short)f2b(v0.w);
      f[4] = (short)f2b(v1.x); f[5] = (short)f2b(v1.y);
      f[6] = (short)f2b(v1.z); f[7] = (short)f2b(v1.w);
      bf[T2][kb] = f;
    }
  }
  const f32x4 vzero = {0.f, 0.f, 0.f, 0.f};
  for (int it = 0; it < 4; ++it) {
    const int r0 = (t0 + it) * 64;
    if (r0 >= M) break;   // block-uniform
    {
      const int row = tid >> 2, cb = (tid & 3) * 32;
      union U8 { uint4 v; unsigned short s[8]; } o;
#pragma unroll
      for (int cc = 0; cc < 4; ++cc) {
        const int c8 = cb + cc * 8;
        if (r0 + row < M) {
          const float4 e0 = *(const float4*)(E + (size_t)(r0 + row) * DIM + c8);
          const float4 e1 = *(const float4*)(E + (size_t)(r0 + row) * DIM + c8 + 4);
          o.s[0] = f2b(e0.x); o.s[1] = f2b(e0.y); o.s[2] = f2b(e0.z); o.s[3] = f2b(e0.w);
          o.s[4] = f2b(e1.x); o.s[5] = f2b(e1.y); o.s[6] = f2b(e1.z); o.s[7] = f2b(e1.w);
        } else {
          o.v = make_uint4(0, 0, 0, 0);
        }
        *(uint4*)&A[row][c8] = o.v;
      }
    }
    __syncthreads();
#pragma unroll
    for (int mt = 0; mt < 4; ++mt) {
      short8 af[4];
#pragma unroll
      for (int kb = 0; kb < 4; ++kb) af[kb] = *(const short8*)&A[mt * 16 + m][kb * 32 + q * 8];
      f32x4 acc[2] = {vzero, vzero};
#pragma unroll
      for (int kb = 0; kb < 4; ++kb) {
#pragma unroll
        for (int T2 = 0; T2 < 2; ++T2)
          acc[T2] = __builtin_amdgcn_mfma_f32_16x16x32_bf16(af[kb], bf[T2][kb], acc[T2], 0, 0, 0);
      }
#pragma unroll
      for (int T2 = 0; T2 < 2; ++T2) {
        const int col = 32 * w + 16 * T2 + m;
#pragma unroll
        for (int i = 0; i < 4; ++i) {
          const int r = r0 + mt * 16 + q * 4 + i;
          if (r < M) T[(size_t)r * DIM + col] = f2b(acc[T2][i]);
        }
      }
    }
    __syncthreads();  // A reused by next tile
  }
}

// ---------------- P2 (fallback only): x build
__global__ void build_x_kernel(const int* __restrict__ qs, const int* __restrict__ cs,
                               const int* __restrict__ qds, const int* __restrict__ cds,
                               const int* __restrict__ corr,
                               const unsigned short* __restrict__ Tq, const unsigned short* __restrict__ Tc,
                               const unsigned short* __restrict__ Tqd, const unsigned short* __restrict__ Tcd,
                               const float* __restrict__ bx, unsigned short* __restrict__ xg,
                               float* __restrict__ SSg, float* __restrict__ corrf) {
  const int r = blockIdx.x * 16 + (threadIdx.x >> 4);   // r = s*1024 + b
  const int c8 = (threadIdx.x & 15) * 8;
  const int s = r >> 10, b = r & 1023;
  const int q = qs[b * S_LEN + s], c = cs[b * S_LEN + s];
  const int qd = qds[b * S_LEN + s], cd = cds[b * S_LEN + s];
  union U8 { uint4 v; unsigned short s[8]; };
  U8 vq, vc, vd, ve, o;
  vq.v = *(const uint4*)(Tq + (size_t)q * DIM + c8);
  vc.v = *(const uint4*)(Tc + (size_t)c * DIM + c8);
  vd.v = *(const uint4*)(Tqd + (size_t)qd * DIM + c8);
  ve.v = *(const uint4*)(Tcd + (size_t)cd * DIM + c8);
  const float4 bx0 = *(const float4*)(bx + c8);
  const float4 bx1 = *(const float4*)(bx + c8 + 4);
  float bb[8] = {bx0.x, bx0.y, bx0.z, bx0.w, bx1.x, bx1.y, bx1.z, bx1.w};
  float part = 0.f;
#pragma unroll
  for (int j = 0; j < 8; ++j) {
    const float sv = b2f(vq.s[j]) + b2f(vc.s[j]) + b2f(vd.s[j]) + b2f(ve.s[j]) + bb[j];
    o.s[j] = f2b(sv);
    const float xr = b2f(o.s[j]);
    part = fmaf(xr, xr, part);
  }
  *(uint4*)(xg + (size_t)r * DIM + c8) = o.v;
#pragma unroll
  for (int off = 1; off <= 8; off <<= 1) part += __shfl_xor(part, off, 64);
  if ((threadIdx.x & 15) == 0) {
    SSg[r] = part;
    corrf[r] = (float)corr[b * S_LEN + s];
  }
}

// ---------------- P3 (fallback only): GG gemm
__global__ void gemm_xg_kernel(const unsigned short* __restrict__ xg,
                               const float* __restrict__ Wk,
                               const int* __restrict__ corr, const int* __restrict__ qds,
                               const int* __restrict__ cds,
                               const float* __restrict__ Tkc,
                               const unsigned short* __restrict__ Tkqd,
                               const unsigned short* __restrict__ Tkcd,
                               unsigned short* __restrict__ GG) {
  const int tid = threadIdx.x;
  const int r0 = blockIdx.x * 64;   // r = t*1024 + b, t <= 198
  __shared__ __align__(16) unsigned short TS[64][136];
  {
    const int row = tid >> 2, cb = (tid & 3) * 32;
    const int r = r0 + row, t = r >> 10, b = r & 1023;
    const int ci = corr[b * S_LEN + t], qi = qds[b * S_LEN + t], di = cds[b * S_LEN + t];
    union U8 { uint4 v; unsigned short s[8]; };
#pragma unroll
    for (int cc = 0; cc < 4; ++cc) {
      const int c8 = cb + cc * 8;
      U8 vq, vc, o;
      vq.v = *(const uint4*)(Tkqd + (size_t)qi * DIM + c8);
      vc.v = *(const uint4*)(Tkcd + (size_t)di * DIM + c8);
      const float4 k0 = *(const float4*)(Tkc + (size_t)ci * DIM + c8);
      const float4 k1 = *(const float4*)(Tkc + (size_t)ci * DIM + c8 + 4);
      float kk[8] = {k0.x, k0.y, k0.z, k0.w, k1.x, k1.y, k1.z, k1.w};
#pragma unroll
      for (int j = 0; j < 8; ++j) o.s[j] = f2b(kk[j] + b2f(vq.s[j]) + b2f(vc.s[j]));
      *(uint4*)&TS[row][c8] = o.v;
    }
  }
  __syncthreads();
  const int w = tid >> 6, L = tid & 63, q = L >> 4, m = L & 15;
  short8 wk[2][4];
#pragma unroll
  for (int T = 0; T < 2; ++T) {
    const int n = 32 * w + 16 * T + m;
#pragma unroll
    for (int kb = 0; kb < 4; ++kb) {
      const float* src = Wk + (size_t)n * 512 + kb * 32 + q * 8;
      const float4 v0 = *(const float4*)src;
      const float4 v1 = *(const float4*)(src + 4);
      short8 f;
      f[0] = (short)f2b(v0.x); f[1] = (short)f2b(v0.y);
      f[2] = (short)f2b(v0.z); f[3] = (short)f2b(v0.w);
      f[4] = (short)f2b(v1.x); f[5] = (short)f2b(v1.y);
      f[6] = (short)f2b(v1.z); f[7] = (short)f2b(v1.w);
      wk[T][kb] = f;
    }
  }
  const f32x4 vzero = {0.f, 0.f, 0.f, 0.f};
#pragma unroll
  for (int mt = 0; mt < 4; ++mt) {
    short8 af[4];
#pragma unroll
    for (int kb = 0; kb < 4; ++kb)
      af[kb] = *(const short8*)(xg + (size_t)(r0 + mt * 16 + m) * DIM + kb * 32 + q * 8);
    f32x4 acc[2] = {vzero, vzero};
#pragma unroll
    for (int kb = 0; kb < 4; ++kb) {
#pragma unroll
      for (int T = 0; T < 2; ++T)
        acc[T] = __builtin_amdgcn_mfma_f32_16x16x32_bf16(af[kb], wk[T][kb], acc[T], 0, 0, 0);
    }
#pragma unroll
    for (int T = 0; T < 2; ++T) {
      const int col = 32 * w + 16 * T + m;
#pragma unroll
      for (int i = 0; i < 4; ++i) {
        const int row64 = mt * 16 + q * 4 + i;
        GG[(size_t)(r0 + row64) * DIM + col] = f2b(acc[T][i] + b2f(TS[row64][col]));
      }
    }
  }
}

// ---------------- producer body: per item (t,c): build 64 x-rows (X/SS/corrf)
// + table-sum TS in LDS, then MFMA them against Wk -> GG. 512 thr / 8 waves.
__device__ __forceinline__ void producer_body(
    const int p,
    const int* __restrict__ qs, const int* __restrict__ cs,
    const int* __restrict__ qds, const int* __restrict__ cds,
    const int* __restrict__ corr,
    const unsigned short* __restrict__ Tq, const unsigned short* __restrict__ Tc,
    const unsigned short* __restrict__ Tqd, const unsigned short* __restrict__ Tcd,
    const float* __restrict__ bx, const float* __restrict__ Wk,
    const float* __restrict__ Tkc, const unsigned short* __restrict__ Tkqd,
    const unsigned short* __restrict__ Tkcd,
    unsigned short* __restrict__ X, unsigned short* __restrict__ GG,
    float* __restrict__ SSg, float* __restrict__ corrf,
    int* donecnt, unsigned short (*xtile)[136], unsigned short (*TS)[136]) {
  const int tid = threadIdx.x;
  const int w = tid >> 6, L = tid & 63, q = L >> 4, m = L & 15;
  const int n = 16 * w + m;
  short8 wk[4];
#pragma unroll
  for (int kb = 0; kb < 4; ++kb) {
    const float* src = Wk + (size_t)n * 512 + kb * 32 + q * 8;
    const float4 v0 = *(const float4*)src;
    const float4 v1 = *(const float4*)(src + 4);
    short8 f;
    f[0] = (short)f2b(v0.x); f[1] = (short)f2b(v0.y);
    f[2] = (short)f2b(v0.z); f[3] = (short)f2b(v0.w);
    f[4] = (short)f2b(v1.x); f[5] = (short)f2b(v1.y);
    f[6] = (short)f2b(v1.z); f[7] = (short)f2b(v1.w);
    wk[kb] = f;
  }
  const int row = tid >> 3, k8 = tid & 7;
  const int c0 = k8 * 16;
  float bxv[16];
#pragma unroll
  for (int j = 0; j < 4; ++j) {
    const float4 bv = *(const float4*)(bx + c0 + j * 4);
    bxv[4 * j + 0] = bv.x; bxv[4 * j + 1] = bv.y;
    bxv[4 * j + 2] = bv.z; bxv[4 * j + 3] = bv.w;
  }
  const f32x4 vzero = {0.f, 0.f, 0.f, 0.f};
  union U8 { uint4 v; unsigned short s[8]; };

  for (int i = p; i < 3200; i += NPROD) {
    const int t = i >> 4, c = i & 15;
    const int b = c * 64 + row;
    const int base = b * S_LEN + t;
    const int qi = qs[base], ci = cs[base], qdi = qds[base], cdi = cds[base], cri = corr[base];
    float part = 0.f;
#pragma unroll
    for (int jj = 0; jj < 2; ++jj) {
      const int c8 = c0 + jj * 8;
      U8 vq, vc, vd, ve, o;
      vq.v = *(const uint4*)(Tq + (size_t)qi * DIM + c8);
      vc.v = *(const uint4*)(Tc + (size_t)ci * DIM + c8);
      vd.v = *(const uint4*)(Tqd + (size_t)qdi * DIM + c8);
      ve.v = *(const uint4*)(Tcd + (size_t)cdi * DIM + c8);
#pragma unroll
      for (int j = 0; j < 8; ++j) {
        const float sv = b2f(vq.s[j]) + b2f(vc.s[j]) + b2f(vd.s[j]) + b2f(ve.s[j]) + bxv[jj * 8 + j];
        o.s[j] = f2b(sv);
        const float xr = b2f(o.s[j]);
        part = fmaf(xr, xr, part);
      }
      *(uint4*)&xtile[row][c8] = o.v;
      *(uint4*)(X + (size_t)(t * 1024 + b) * DIM + c8) = o.v;
    }
#pragma unroll
    for (int off2 = 1; off2 <= 4; off2 <<= 1) part += __shfl_xor(part, off2, 64);
    if (k8 == 0) {
      SSg[t * 1024 + b] = part;
      corrf[t * 1024 + b] = (float)cri;
    }
    if (t < 199) {
#pragma unroll
      for (int jj = 0; jj < 2; ++jj) {
        const int c8 = c0 + jj * 8;
        U8 vq, vc, o;
        vq.v = *(const uint4*)(Tkqd + (size_t)qdi * DIM + c8);
        vc.v = *(const uint4*)(Tkcd + (size_t)cdi * DIM + c8);
        const float4 k0 = *(const float4*)(Tkc + (size_t)cri * DIM + c8);
        const float4 k1 = *(const float4*)(Tkc + (size_t)cri * DIM + c8 + 4);
        float kk[8] = {k0.x, k0.y, k0.z, k0.w, k1.x, k1.y, k1.z, k1.w};
#pragma unroll
        for (int j = 0; j < 8; ++j) o.s[j] = f2b(kk[j] + b2f(vq.s[j]) + b2f(vc.s[j]));
        *(uint4*)&TS[row][c8] = o.v;
      }
    }
    __syncthreads();
    if (t < 199) {
#pragma unroll
      for (int mt = 0; mt < 4; ++mt) {
        short8 af[4];
#pragma unroll
        for (int kb = 0; kb < 4; ++kb) af[kb] = *(const short8*)&xtile[mt * 16 + m][kb * 32 + q * 8];
        f32x4 acc = vzero;
#pragma unroll
        for (int kb = 0; kb < 4; ++kb)
          acc = __builtin_amdgcn_mfma_f32_16x16x32_bf16(af[kb], wk[kb], acc, 0, 0, 0);
#pragma unroll
        for (int i2 = 0; i2 < 4; ++i2) {
          const int row64 = mt * 16 + q * 4 + i2;
          GG[(size_t)(t * 1024 + c * 64 + row64) * DIM + n] = f2b(acc[i2] + b2f(TS[row64][n]));
        }
      }
    }
    __syncthreads();  // all stores drained (vmcnt(0) before s_barrier) + xtile reuse
    if (tid == 0)
      __hip_atomic_fetch_add(donecnt + t, 1, __ATOMIC_RELEASE, __HIP_MEMORY_SCOPE_AGENT);
  }
}

// ---------------- the recurrence (consumer). Identical math to R6 scan_kernel;
// PIPE adds watermark waits before prefetch issue.
template <bool PIPE>
__device__ __forceinline__ void scan_body(
    const unsigned short* __restrict__ xg, const unsigned short* __restrict__ gg,
    const float* __restrict__ SSg, const float* __restrict__ corrf,
    const float* __restrict__ h0,
    const float* __restrict__ Ws1, const float* __restrict__ bs1,
    const float* __restrict__ Ws2, const float* __restrict__ bs2,
    const float* __restrict__ Wp1, const float* __restrict__ Wp2,
    const float* __restrict__ Wk,
    const float* __restrict__ gTp1c, const float* __restrict__ gTp2c,
    float* __restrict__ outp, int* wmp, unsigned short* ldsbase) {
  unsigned short (*Sbuf)[136] = (unsigned short (*)[136])ldsbase;
  unsigned short (*Pbuf)[136] = (unsigned short (*)[136])(ldsbase + 16 * 136);

  const int tid = threadIdx.x;
  const int w = tid >> 6, L = tid & 63, q = L >> 4, m = L & 15;
  const int col16 = 16 * w + m;
  const int rbase = blockIdx.x << 4;
  const size_t SB = (size_t)NBATCH * DIM;

  short8 wf[5][4];
  {
    const float* Wptr[5] = {Ws1, Ws2, Wp1, Wp2, Wk};
    const int ldw[5] = {128, 128, 256, 256, 512};
#pragma unroll
    for (int M = 0; M < 5; ++M) {
#pragma unroll
      for (int kb = 0; kb < 4; ++kb) {
        const float* src = Wptr[M] + (size_t)col16 * ldw[M] + kb * 32 + q * 8;
        const float4 v0 = *(const float4*)src;
        const float4 v1 = *(const float4*)(src + 4);
        short8 f;
        f[0] = (short)f2b(v0.x); f[1] = (short)f2b(v0.y);
        f[2] = (short)f2b(v0.z); f[3] = (short)f2b(v0.w);
        f[4] = (short)f2b(v1.x); f[5] = (short)f2b(v1.y);
        f[6] = (short)f2b(v1.z); f[7] = (short)f2b(v1.w);
        wf[M][kb] = f;
      }
    }
  }
  const float bs1v = bs1[col16], bs2v = bs2[col16];
  const float tp1v0 = gTp1c[col16], dtp1 = gTp1c[DIM + col16] - tp1v0;
  const float tp2v0 = gTp2c[col16], dtp2 = gTp2c[DIM + col16] - tp2v0;
  if (tid < 16) outp[(size_t)(rbase + tid) * S_LEN + (S_LEN - 1)] = 0.0f;

  int wm_seen = 0;
  auto wait_wm = [&](int need) {
    if (wm_seen >= need) return;
    // relaxed polling (no per-poll cache-inv), one acquire load once satisfied
    while (__hip_atomic_load(wmp, __ATOMIC_RELAXED, __HIP_MEMORY_SCOPE_AGENT) < need)
      __builtin_amdgcn_s_sleep(8);
    wm_seen = __hip_atomic_load(wmp, __ATOMIC_ACQUIRE, __HIP_MEMORY_SCOPE_AGENT);
  };
  if (PIPE) wait_wm(3);  // prologue touches t = 0..2

  float h[4];
#pragma unroll
  for (int i = 0; i < 4; ++i) {
    const int b = rbase + q * 4 + i;
    const float hv = h0[(size_t)b * DIM + col16];
    h[i] = hv;
    const float xt = b2f(xg[(size_t)b * DIM + col16]);
    Sbuf[q * 4 + i][col16] = f2b(xt - hv);
  }
  float* poy = outp + (size_t)(rbase + m) * S_LEN;   // wave0 y stores, imm-offset t

  // distance-2 prefetch: register sets A/B + walking pointers (imm offsets)
  unsigned short XPA[4], XPB[4], GPA[4], GPB[4];
  float4 CFA, CFB;
  short8 XFA[4], XFB[4];
  float SSA, SSB;
  const unsigned short* pxA = xg + 3 * SB + (size_t)(rbase + q * 4) * DIM + col16;
  const unsigned short* pxB = pxA + SB;
  const unsigned short* pgA = gg + 2 * SB + (size_t)(rbase + q * 4) * DIM + col16;
  const unsigned short* pgB = pgA + SB;
  const float* pcA = corrf + 2 * NBATCH + rbase + q * 4;
  const float* pcB = pcA + NBATCH;
  const unsigned short* pfA = xg + 2 * SB + (size_t)(rbase + m) * DIM + q * 8;
  const unsigned short* pfB = pfA + SB;
  const float* psA = SSg + 2 * NBATCH + rbase + m;
  const float* psB = psA + NBATCH;
#pragma unroll
  for (int i = 0; i < 4; ++i) {
    XPA[i] = xg[SB + (size_t)(rbase + q * 4 + i) * DIM + col16];      // x[1]
    XPB[i] = xg[2 * SB + (size_t)(rbase + q * 4 + i) * DIM + col16];  // x[2]
    GPA[i] = gg[(size_t)(rbase + q * 4 + i) * DIM + col16];           // gg[0]
    GPB[i] = gg[SB + (size_t)(rbase + q * 4 + i) * DIM + col16];      // gg[1]
  }
  CFA = *(const float4*)(corrf + rbase + q * 4);
  CFB = *(const float4*)(corrf + NBATCH + rbase + q * 4);
#pragma unroll
  for (int kb = 0; kb < 4; ++kb) {
    XFA[kb] = *(const short8*)(xg + (size_t)(rbase + m) * DIM + kb * 32 + q * 8);        // x[0]
    XFB[kb] = *(const short8*)(xg + SB + (size_t)(rbase + m) * DIM + kb * 32 + q * 8);   // x[1]
  }
  SSA = SSg[rbase + m];
  SSB = SSg[NBATCH + rbase + m];

  const f32x4 vzero = {0.f, 0.f, 0.f, 0.f};

#define STEP(TCUR, XP, GP, CF, PX, PG, PC, XF, SSR, PF, PS)                    \
  do {                                                                         \
    const int t_ = (TCUR);                                                     \
    float xnv[4], ggv[4], cfv[4];                                              \
    _Pragma("unroll") for (int i = 0; i < 4; ++i) {                            \
      xnv[i] = b2f(XP[i]); ggv[i] = b2f(GP[i]);                                \
    }                                                                          \
    cfv[0] = CF.x; cfv[1] = CF.y; cfv[2] = CF.z; cfv[3] = CF.w;                \
    short8 xfr[4]; float ssv = SSR;                                            \
    if (w == 0) {                                                              \
      _Pragma("unroll") for (int kb = 0; kb < 4; ++kb) xfr[kb] = XF[kb];       \
    }                                                                          \
    _Pragma("unroll") for (int i = 0; i < 4; ++i) {                            \
      XP[i] = PX[i * DIM]; GP[i] = PG[i * DIM];                                \
    }                                                                          \
    CF = *(const float4*)PC;                                                   \
    PX += 2 * SB; PG += 2 * SB; PC += 2 * NBATCH;                              \
    if (w == 0) {                                                              \
      _Pragma("unroll") for (int kb = 0; kb < 4; ++kb)                         \
        XF[kb] = *(const short8*)(PF + kb * 32);                               \
      SSR = *PS;                                                               \
      PF += 2 * SB; PS += 2 * NBATCH;                                          \
    }                                                                          \
    wg_barrier_lds(); /* Sbuf(t) ready */                                      \
    short8 sf[4];                                                              \
    _Pragma("unroll") for (int kb = 0; kb < 4; ++kb)                           \
        sf[kb] = *(const short8*)&Sbuf[m][kb * 32 + q * 8];                    \
    f32x4 a1 = vzero, a2 = vzero, c1 = vzero;                                  \
    _Pragma("unroll") for (int kb = 0; kb < 4; ++kb) {                         \
      a1 = __builtin_amdgcn_mfma_f32_16x16x32_bf16(sf[kb], wf[0][kb], a1, 0, 0, 0); \
      a2 = __builtin_amdgcn_mfma_f32_16x16x32_bf16(sf[kb], wf[1][kb], a2, 0, 0, 0); \
      c1 = __builtin_amdgcn_mfma_f32_16x16x32_bf16(sf[kb], wf[4][kb], c1, 0, 0, 0); \
    }                                                                          \
    if (w == 0) {                                                              \
      f32x4 dt = vzero;                                                        \
      _Pragma("unroll") for (int kb = 0; kb < 4; ++kb)                         \
        dt = __builtin_amdgcn_mfma_f32_16x16x32_bf16(sf[kb], xfr[kb], dt, 0, 0, 0); \
      if (t_ > 0 && q == (m >> 2)) {                                           \
        const int ii = m & 3;                                                  \
        const float D = ii == 0 ? dt[0] : ii == 1 ? dt[1] : ii == 2 ? dt[2] : dt[3]; \
        poy[t_ - 1] = fast_sigmoid(ssv - D);                                   \
      }                                                                        \
    }                                                                          \
    _Pragma("unroll") for (int i2 = 0; i2 < 2; ++i2) {                         \
      const float s0 = fast_sigmoid(a1[2 * i2] + bs1v) * fast_tanh(a2[2 * i2] + bs2v); \
      const float s1 = fast_sigmoid(a1[2 * i2 + 1] + bs1v) * fast_tanh(a2[2 * i2 + 1] + bs2v); \
      const unsigned u = pk_bf16(s0, s1);                                      \
      Pbuf[q * 4 + 2 * i2][col16] = (unsigned short)u;                         \
      Pbuf[q * 4 + 2 * i2 + 1][col16] = (unsigned short)(u >> 16);             \
    }                                                                          \
    wg_barrier_lds(); /* Pbuf ready */                                         \
    short8 pf[4];                                                              \
    _Pragma("unroll") for (int kb = 0; kb < 4; ++kb)                           \
        pf[kb] = *(const short8*)&Pbuf[m][kb * 32 + q * 8];                    \
    f32x4 p1 = vzero, p2 = vzero;                                              \
    _Pragma("unroll") for (int kb = 0; kb < 4; ++kb) {                         \
      p1 = __builtin_amdgcn_mfma_f32_16x16x32_bf16(pf[kb], wf[2][kb], p1, 0, 0, 0); \
      p2 = __builtin_amdgcn_mfma_f32_16x16x32_bf16(pf[kb], wf[3][kb], p2, 0, 0, 0); \
    }                                                                          \
    float sn[4];                                                               \
    _Pragma("unroll") for (int i = 0; i < 4; ++i) {                            \
      const float g = fast_sigmoid(ggv[i] - c1[i]);                            \
      const float t1v = fmaf(cfv[i], dtp1, tp1v0);                             \
      const float t2v = fmaf(cfv[i], dtp2, tp2v0);                             \
      const float pka = fast_sigmoid(p1[i] + t1v) * fast_tanh(p2[i] + t2v);    \
      const float hn = pka + g * (h[i] - pka);                                 \
      h[i] = hn;                                                               \
      sn[i] = xnv[i] - hn;                                                     \
    }                                                                          \
    _Pragma("unroll") for (int i2 = 0; i2 < 2; ++i2) {                         \
      const unsigned u = pk_bf16(sn[2 * i2], sn[2 * i2 + 1]);                  \
      Sbuf[q * 4 + 2 * i2][col16] = (unsigned short)u;                         \
      Sbuf[q * 4 + 2 * i2 + 1][col16] = (unsigned short)(u >> 16);             \
    }                                                                          \
  } while (0)

  for (int t2 = 0; t2 < 198; t2 += 2) {
    if (PIPE) {  // pair (t2,t2+1) prefetches up to t2+4
      const int need = (t2 + 5 > 200) ? 200 : t2 + 5;
      wait_wm(need);
    }
    STEP(t2, XPA, GPA, CFA, pxA, pgA, pcA, XFA, SSA, pfA, psA);
    STEP(t2 + 1, XPB, GPB, CFB, pxB, pgB, pcB, XFB, SSB, pfB, psB);
  }
  STEP(198, XPA, GPA, CFA, pxA, pgA, pcA, XFA, SSA, pfA, psA);
#undef STEP

  // epilogue: y(198) from s(199) in Sbuf, x[199] (= XFB), ss[199] (= SSB)
  wg_barrier_lds();
  if (w == 0) {
    short8 sf[4];
#pragma unroll
    for (int kb = 0; kb < 4; ++kb) sf[kb] = *(const short8*)&Sbuf[m][kb * 32 + q * 8];
    f32x4 dt = vzero;
#pragma unroll
    for (int kb = 0; kb < 4; ++kb)
      dt = __builtin_amdgcn_mfma_f32_16x16x32_bf16(sf[kb], XFB[kb], dt, 0, 0, 0);
    if (q == (m >> 2)) {
      const int ii = m & 3;
      const float D = ii == 0 ? dt[0] : ii == 1 ? dt[1] : ii == 2 ? dt[2] : dt[3];
      poy[S_LEN - 2] = fast_sigmoid(SSB - D);
    }
  }
}

// ---------------- fused kernel: [0,64) scan | [64,255) producers | 255 sweeper
template <bool PIPE>
__global__ __launch_bounds__(512, 2) void scan_fused_kernel(
    const unsigned short* __restrict__ xg, const unsigned short* __restrict__ gg,
    const float* __restrict__ SSg, const float* __restrict__ corrf,
    const float* __restrict__ h0,
    const float* __restrict__ Ws1, const float* __restrict__ bs1,
    const float* __restrict__ Ws2, const float* __restrict__ bs2,
    const float* __restrict__ Wp1, const float* __restrict__ Wp2,
    const float* __restrict__ WkF,
    const float* __restrict__ gTp1c, const float* __restrict__ gTp2c,
    float* __restrict__ outp,
    const int* __restrict__ qs, const int* __restrict__ cs,
    const int* __restrict__ qds, const int* __restrict__ cds,
    const int* __restrict__ corr,
    const unsigned short* __restrict__ Tq, const unsigned short* __restrict__ Tc,
    const unsigned short* __restrict__ Tqd, const unsigned short* __restrict__ Tcd,
    const float* __restrict__ bx, const float* __restrict__ Tkc,
    const unsigned short* __restrict__ Tkqd, const unsigned short* __restrict__ Tkcd,
    unsigned short* __restrict__ Xw, unsigned short* __restrict__ GGw,
    float* __restrict__ SSw, float* __restrict__ corrw,
    int* donecnt, int* wmp) {
  __shared__ __align__(16) unsigned short lds[PIPE ? 2 * 64 * 136 : 2 * 16 * 136];
  if (!PIPE || blockIdx.x < 64) {
    scan_body<PIPE>(xg, gg, SSg, corrf, h0, Ws1, bs1, Ws2, bs2, Wp1, Wp2, WkF,
                    gTp1c, gTp2c, outp, wmp, lds);
    return;
  }
  if constexpr (PIPE) {
    if (blockIdx.x == 255) {
      // wave-parallel sweep: 64 lanes poll donecnt[base..base+63] (coalesced),
      // ballot the contiguous done-prefix, publish wm once per round.
      if (threadIdx.x < 64) {
        const int lane = threadIdx.x;
        int base = 0;
        while (base < S_LEN) {
          const int t = base + lane;
          const int v = (t < S_LEN)
              ? __hip_atomic_load(donecnt + t, __ATOMIC_RELAXED, __HIP_MEMORY_SCOPE_AGENT)
              : 16;
          const unsigned long long ball = __ballot(v >= 16);
          const unsigned long long nb = ~ball;
          int adv = nb ? (__ffsll((unsigned long long)nb) - 1) : 64;
          if (adv > S_LEN - base) adv = S_LEN - base;
          if (adv > 0) {
            if (lane == 0) {
              (void)__hip_atomic_load(donecnt + base + adv - 1, __ATOMIC_ACQUIRE,
                                      __HIP_MEMORY_SCOPE_AGENT);
              __hip_atomic_store(wmp, base + adv, __ATOMIC_RELEASE,
                                 __HIP_MEMORY_SCOPE_AGENT);
            }
            base += adv;
          } else {
            __builtin_amdgcn_s_sleep(2);
          }
        }
      }
      return;
    }
    producer_body(blockIdx.x - 64, qs, cs, qds, cds, corr, Tq, Tc, Tqd, Tcd, bx,
                  WkF, Tkc, Tkqd, Tkcd, Xw, GGw, SSw, corrw, donecnt,
                  (unsigned short (*)[136])lds,
                  (unsigned short (*)[136])(lds + 64 * 136));
  }
}

extern "C" void kernel_launch(void* const* d_in, const int* in_sizes, int n_in,
                              void* d_out, int out_size, void* d_ws, size_t ws_size,
                              hipStream_t stream) {
  const int* qs    = (const int*)d_in[0];
  const int* cs    = (const int*)d_in[1];
  const int* qds   = (const int*)d_in[2];
  const int* cds   = (const int*)d_in[3];
  const int* corr  = (const int*)d_in[4];
  const float* Eq    = (const float*)d_in[5];
  const float* Ec    = (const float*)d_in[6];
  const float* Eqd   = (const float*)d_in[7];
  const float* Ecd   = (const float*)d_in[8];
  const float* Ecorr = (const float*)d_in[9];
  const float* Wx  = (const float*)d_in[10];
  const float* bx  = (const float*)d_in[11];
  const float* Ws1 = (const float*)d_in[12];
  const float* bs1 = (const float*)d_in[13];
  const float* Ws2 = (const float*)d_in[14];
  const float* bs2 = (const float*)d_in[15];
  const float* Wp1 = (const float*)d_in[16];
  const float* bp1 = (const float*)d_in[17];
  const float* Wp2 = (const float*)d_in[18];
  const float* bp2 = (const float*)d_in[19];
  const float* Wk  = (const float*)d_in[20];
  const float* bk  = (const float*)d_in[21];
  const float* h0  = (const float*)d_in[22];

  char* ws = (char*)d_ws;
  const size_t xbytes = (size_t)S_LEN * NBATCH * DIM * 2;
  const size_t ggbytes = (size_t)(S_LEN - 1) * NBATCH * DIM * 2;

  // ---- fused (non-aliased) layout: X | GG | corrf | SS | tables | sync.
  // Prefetch overruns (<=2 steps past X/GG/corrf/SS ends) land in the next
  // region -- harmless garbage reads inside d_ws, never consumed.
  {
    size_t off = 0;
    auto alloc = [&](size_t bytes) {
      void* p = ws + off;
      off = (off + bytes + 255) & ~(size_t)255;
      return p;
    };
    unsigned short* X  = (unsigned short*)alloc(xbytes);
    unsigned short* GG = (unsigned short*)alloc(ggbytes);
    float* corrf = (float*)alloc((size_t)S_LEN * NBATCH * 4);
    float* SS    = (float*)alloc((size_t)S_LEN * NBATCH * 4);
    unsigned short* Tq  = (unsigned short*)alloc((size_t)50000 * DIM * 2);
    unsigned short* Tc  = (unsigned short*)alloc((size_t)1000 * DIM * 2);
    unsigned short* Tqd = (unsigned short*)alloc((size_t)101 * DIM * 2);
    unsigned short* Tcd = (unsigned short*)alloc((size_t)101 * DIM * 2);
    unsigned short* Tkqd = (unsigned short*)alloc((size_t)101 * DIM * 2);
    unsigned short* Tkcd = (unsigned short*)alloc((size_t)101 * DIM * 2);
    float* Tkc  = (float*)alloc((size_t)2 * DIM * 4);
    float* Tp1c = (float*)alloc((size_t)2 * DIM * 4);
    float* Tp2c = (float*)alloc((size_t)2 * DIM * 4);
    int* syncz  = (int*)alloc(2048);   // donecnt[256] + wm
    if (off <= ws_size) {
      proj_all_kernel<<<304, 256, 0, stream>>>(Eq, Ec, Eqd, Ecd, Ecorr, Wx,
                                               Wp1, bp1, Wp2, bp2, Wk, bk,
                                               Tq, Tc, Tqd, Tcd, Tkqd, Tkcd,
                                               Tkc, Tp1c, Tp2c, syncz);
      scan_fused_kernel<true><<<256, 512, 0, stream>>>(
          X, GG, SS, corrf, h0, Ws1, bs1, Ws2, bs2, Wp1, Wp2, Wk, Tp1c, Tp2c,
          (float*)d_out, qs, cs, qds, cds, corr, Tq, Tc, Tqd, Tcd, bx,
          Tkc, Tkqd, Tkcd, X, GG, SS, corrf, syncz, syncz + 256);
      return;
    }
  }

  // ---- fallback: original 4-kernel path (GG aliases Tq..Tcd during build)
  const size_t A = (xbytes + 255) & ~(size_t)255;
  unsigned short* X  = (unsigned short*)ws;
  unsigned short* GG = (unsigned short*)(ws + A);
  unsigned short* Tq  = GG;  // alias (dead after build_x)
  unsigned short* Tc  = (unsigned short*)(ws + A + (size_t)50000 * DIM * 2);
  unsigned short* Tqd = (unsigned short*)(ws + A + (size_t)51000 * DIM * 2);
  unsigned short* Tcd = (unsigned short*)(ws + A + (size_t)51101 * DIM * 2);
  size_t off = A + ((ggbytes + 255) & ~(size_t)255);
  auto alloc = [&](size_t bytes) {
    void* p = ws + off;
    off = (off + bytes + 255) & ~(size_t)255;
    return p;
  };
  float* corrf = (float*)alloc((size_t)S_LEN * NBATCH * 4);
  float* SS    = (float*)alloc((size_t)S_LEN * NBATCH * 4);
  unsigned short* Tkqd = (unsigned short*)alloc((size_t)101 * DIM * 2);
  unsigned short* Tkcd = (unsigned short*)alloc((size_t)101 * DIM * 2);
  float* Tkc  = (float*)alloc((size_t)2 * DIM * 4);
  float* Tp1c = (float*)alloc((size_t)2 * DIM * 4);
  float* Tp2c = (float*)alloc((size_t)2 * DIM * 4);
  int* syncz  = (int*)alloc(2048);

  proj_all_kernel<<<304, 256, 0, stream>>>(Eq, Ec, Eqd, Ecd, Ecorr, Wx,
                                           Wp1, bp1, Wp2, bp2, Wk, bk,
                                           Tq, Tc, Tqd, Tcd, Tkqd, Tkcd, Tkc, Tp1c, Tp2c,
                                           syncz);
  build_x_kernel<<<(S_LEN * NBATCH) / 16, 256, 0, stream>>>(qs, cs, qds, cds, corr,
                                                            Tq, Tc, Tqd, Tcd, bx, X, SS, corrf);
  gemm_xg_kernel<<<((S_LEN - 1) * NBATCH) / 64, 256, 0, stream>>>(X, Wk, corr, qds, cds,
                                                                  Tkc, Tkqd, Tkcd, GG);
  scan_fused_kernel<false><<<64, 512, 0, stream>>>(
      X, GG, SS, corrf, h0, Ws1, bs1, Ws2, bs2, Wp1, Wp2, Wk, Tp1c, Tp2c,
      (float*)d_out, qs, cs, qds, cds, corr, Tq, Tc, Tqd, Tcd, bx,
      Tkc, Tkqd, Tkcd, X, GG, SS, corrf, syncz, syncz + 256);
}